// Round 14
// baseline (304.246 us; speedup 1.0000x reference)
//
#include <hip/hip_runtime.h>
#include <stdint.h>
#include <stddef.h>

// ---------------- problem dims ----------------
#define BATCH   4
#define SEQLEN  2048
#define HM      1024
#define DINNER  2048
#define NH      8
#define HD      256
#define NS      64
#define CONVD   2176
#define DCONV   16
#define DPROJ   4232
#define ROWS    (BATCH*SEQLEN)  // 8192
#define QC      256             // big-chunk length
#define NC      (SEQLEN/QC)     // 8 big-chunks
#define SC      64              // sub-chunk length (passC)
#define TT      16              // conv timesteps per thread

typedef __attribute__((ext_vector_type(8))) short short8;
typedef __attribute__((ext_vector_type(4))) short short4v;
typedef __attribute__((ext_vector_type(4))) float f32x4;

// ---------------- workspace layout (bytes) ----------------
static constexpr size_t O_WOUT   = 0;                    //  4,194,304
static constexpr size_t O_WNL    = 4194304;              //  2,097,152
static constexpr size_t O_DT     = 6291456;              //    262,144
static constexpr size_t O_LDA    = 6553600;              //    262,144
static constexpr size_t O_PG     = 6815744;              //      4,096
static constexpr size_t O_BT     = 6819840;              //  1,048,576
static constexpr size_t O_ZB     = 7868416;              // 33,554,432  bf16 z[8192][2048]
static constexpr size_t O_XBCPRE = 41422848;             // 35,651,584  bf16 [8192][2176]
static constexpr size_t O_SG     = O_XBCPRE;             // 16,777,216  f32 [65536][64]
static constexpr size_t O_HG     = O_XBCPRE + 16777216;  // 16,777,216  f32 [256][16384]
static constexpr size_t O_TB     = O_XBCPRE;             // 16,777,216  bf16 [8192][1024]
static constexpr size_t O_XBC    = 77074432;             // bc[8192][128] bf16 (2MB)
static constexpr size_t O_XTR    = 112726016;            // 33,554,432  bf16 xT[2048][8192]
static constexpr size_t O_XBF    = O_XTR;                // 16,777,216  bf16 [8192][1024]
static constexpr size_t O_WIN    = O_XTR + 16777216;     //  8,912,896  bf16 [4352][1024]
static constexpr size_t O_WTAIL  = 146280448;            //     32,768  f32 wtailT[8][1024]
static constexpr size_t O_PSUM   = 146313216;            //  2,097,152  f32 psum[8192][64]
static constexpr size_t O_INVR   = 148410368;            //     32,768  f32 invr[8192]
// END = 148,443,136  (round-2 layout proved ws_size >= 156,241,920)

// ---------------- helpers ----------------
__device__ __forceinline__ short f2bf(float f) {
  union { float f; uint32_t u; } v; v.f = f;
  uint32_t r = v.u + 0x7fffu + ((v.u >> 16) & 1u);
  return (short)(r >> 16);
}

__device__ __forceinline__ float bf2f(short s) {
  union { float f; uint32_t u; } v;
  v.u = ((uint32_t)(uint16_t)s) << 16;
  return v.f;
}

__device__ __forceinline__ void gload_lds16(const void* g, void* l) {
  __builtin_amdgcn_global_load_lds(
      (const __attribute__((address_space(1))) uint32_t*)g,
      (__attribute__((address_space(3))) uint32_t*)l, 16, 0, 0);
}

__device__ __forceinline__ float sigmoidf_fast(float x) {
  return 1.f / (1.f + __expf(-x));
}

// fragment read from a [rows][64-elem] bf16 LDS tile (128B rows, XOR-swizzled)
__device__ __forceinline__ short8 fragr(const char* base, int row, int kbyte) {
  return *(const short8*)(base + row * 128 + (kbyte ^ ((row & 7) << 4)));
}

// ---------------- combined weight prep: 3 transposes + wtail ----------------
// kscale != nullptr: scale source row k by kscale[k] before cast (for W_out*nw)
__device__ __forceinline__ void transpose_tile(const float* __restrict__ W,
                                               short* __restrict__ Wt,
                                               int idx, int srcN, int validN,
                                               int Kdim, int nTilesN, int tid,
                                               const float* __restrict__ kscale) {
  __shared__ short lds[64][72];
  int k0 = (idx / nTilesN) * 64;
  int n0 = (idx % nTilesN) * 64;
  int rr = tid >> 4;
  int cc = (tid & 15) * 4;
#pragma unroll
  for (int pass = 0; pass < 4; ++pass) {
    int k = pass * 16 + rr;
    int gn = n0 + cc;
    f32x4 v = (f32x4)0.f;
    if (gn < validN) v = *(const f32x4*)(W + (size_t)(k0 + k) * srcN + gn);
    if (kscale) {
      float s = kscale[k0 + k];
      v[0] *= s; v[1] *= s; v[2] *= s; v[3] *= s;
    }
    uint32_t p0 = (uint32_t)(uint16_t)f2bf(v[0]) | ((uint32_t)(uint16_t)f2bf(v[1]) << 16);
    uint32_t p1 = (uint32_t)(uint16_t)f2bf(v[2]) | ((uint32_t)(uint16_t)f2bf(v[3]) << 16);
    *(uint32_t*)&lds[k][cc] = p0;
    *(uint32_t*)&lds[k][cc + 2] = p1;
  }
  __syncthreads();
  int n = tid >> 2;
  int ks = (tid & 3) * 16;
  short8 a, b;
#pragma unroll
  for (int j = 0; j < 8; ++j) a[j] = lds[ks + j][n];
#pragma unroll
  for (int j = 0; j < 8; ++j) b[j] = lds[ks + 8 + j][n];
  short* dst = Wt + (size_t)(n0 + n) * Kdim + k0 + ks;
  *(short8*)dst = a;
  *(short8*)(dst + 8) = b;
}

__global__ __launch_bounds__(256)
void prep_weights_kernel(const float* __restrict__ W_in, const float* __restrict__ W_out,
                         const float* __restrict__ W_nl, const float* __restrict__ nw,
                         short* __restrict__ winT, short* __restrict__ woutT,
                         short* __restrict__ wnlT, float* __restrict__ wtailT) {
  int bid = blockIdx.x, tid = threadIdx.x;
  if (bid < 1056) {           // W_in^T: 16 k-tiles x 66 n-tiles (n<4224 only)
    transpose_tile(W_in, winT, bid, DPROJ, DPROJ, HM, 66, tid, nullptr);
  } else if (bid < 1568) {    // W_out^T * nw[k]: 32 k-tiles x 16 n-tiles
    transpose_tile(W_out, woutT, bid - 1056, HM, HM, DINNER, 16, tid, nw);
  } else if (bid < 1824) {    // W_nl^T: 16 x 16
    transpose_tile(W_nl, wnlT, bid - 1568, HM, HM, HM, 16, tid, nullptr);
  } else {                    // wtail: wtailT[h][k] = W_in[k][4224+h]
    int i = (bid - 1824) * 256 + tid;  // 8192 elems
    int h = i >> 10, k = i & 1023;
    wtailT[i] = W_in[(size_t)k * DPROJ + (DPROJ - NH) + h];
  }
}

// ---------------- fused cast x -> bf16 + dt (exact f32 path) ----------------
__global__ __launch_bounds__(256)
void cast_dt_kernel(const float* __restrict__ x, const float* __restrict__ wtailT,
                    const float* __restrict__ dt_bias, const float* __restrict__ A_log,
                    short* __restrict__ xbf, float* __restrict__ dtg,
                    float* __restrict__ ldA) {
  int row = blockIdx.x, tid = threadIdx.x;
  f32x4 xv = ((const f32x4*)(x + (size_t)row * HM))[tid];
  short4v o = { f2bf(xv[0]), f2bf(xv[1]), f2bf(xv[2]), f2bf(xv[3]) };
  ((short4v*)(xbf + (size_t)row * HM))[tid] = o;
  float p[NH];
#pragma unroll
  for (int h = 0; h < NH; ++h) {
    f32x4 w = ((const f32x4*)(wtailT + h * HM))[tid];
    p[h] = xv[0] * w[0] + xv[1] * w[1] + xv[2] * w[2] + xv[3] * w[3];
  }
#pragma unroll
  for (int h = 0; h < NH; ++h)
#pragma unroll
    for (int of = 32; of; of >>= 1) p[h] += __shfl_down(p[h], of);
  __shared__ float red[4][NH];
  int lane = tid & 63, w4 = tid >> 6;
  if (lane == 0)
#pragma unroll
    for (int h = 0; h < NH; ++h) red[w4][h] = p[h];
  __syncthreads();
  if (tid < NH) {
    float s = red[0][tid] + red[1][tid] + red[2][tid] + red[3][tid] + dt_bias[tid];
    float dtv = (s > 20.f) ? s : log1pf(expf(s));
    float A = -expf(A_log[tid]);
    dtg[row * NH + tid] = dtv;
    ldA[row * NH + tid] = dtv * A;
  }
}

// ---------------- parallel inclusive prefix of ldA into aa[257] ------------
__device__ __forceinline__ void prefix_aa(float av, float* aa, float* wsum,
                                          int tid) {
  float v = av;
  int lane = tid & 63;
#pragma unroll
  for (int o = 1; o < 64; o <<= 1) {
    float u = __shfl_up(v, o);
    if (lane >= o) v += u;
  }
  if (lane == 63) wsum[tid >> 6] = v;
  __syncthreads();
  float off = 0.f;
  int w4 = tid >> 6;
#pragma unroll
  for (int w = 0; w < 4; ++w)
    if (w < w4) off += wsum[w];
  aa[tid + 1] = v + off;
  if (tid == 0) aa[0] = 0.f;
  __syncthreads();
}

// ---------------- GEMM1: 256x128 tile, BK=64, 1-phase, 3 blocks/CU ---------
__global__ __launch_bounds__(512)
void gemm1_256(const short* __restrict__ A, const short* __restrict__ B,
               int K, int nTilesN,
               short* __restrict__ Cb, short* __restrict__ Cb2) {
  __shared__ alignas(16) char lds[49152];
  char* As = lds;           // [256][128B]
  char* Bs = lds + 32768;   // [128][128B]
  const int tid = threadIdx.x;
  int bid = blockIdx.x;
  {
    int nwg = gridDim.x;
    if ((nwg & 7) == 0) bid = (bid & 7) * (nwg >> 3) + (bid >> 3);
  }
  const int m0 = (bid / nTilesN) * 256;
  const int n0 = (bid % nTilesN) * 128;
  const int lane = tid & 63;
  const int wid = tid >> 6;        // 8 waves: 4M x 2N
  const int wm = wid >> 1;
  const int wn = wid & 1;
  const int lrow = lane & 15, lk = lane >> 4;

  f32x4 acc[4][4];
#pragma unroll
  for (int i = 0; i < 4; ++i)
#pragma unroll
    for (int j = 0; j < 4; ++j) acc[i][j] = (f32x4)0.f;

  for (int k0 = 0; k0 < K; k0 += 64) {
#pragma unroll
    for (int r = 0; r < 4; ++r) {  // A: 256 rows x 128B
      int p = r * 8192 + tid * 16;
      int row = p >> 7, c = p & 127;
      int sc = c ^ ((row & 7) << 4);
      gload_lds16((const char*)A + ((size_t)(m0 + row) * K + k0) * 2 + sc, As + p);
    }
#pragma unroll
    for (int r = 0; r < 2; ++r) {  // B: 128 rows x 128B
      int p = r * 8192 + tid * 16;
      int row = p >> 7, c = p & 127;
      int sc = c ^ ((row & 7) << 4);
      gload_lds16((const char*)B + ((size_t)(n0 + row) * K + k0) * 2 + sc, Bs + p);
    }
    asm volatile("s_waitcnt vmcnt(0)" ::: "memory");
    __syncthreads();
#pragma unroll
    for (int ks = 0; ks < 2; ++ks) {
      short8 av[4], bv[4];
#pragma unroll
      for (int i = 0; i < 4; ++i) {
        av[i] = fragr(As, wm * 64 + i * 16 + lrow, ks * 64 + lk * 16);
        bv[i] = fragr(Bs, wn * 64 + i * 16 + lrow, ks * 64 + lk * 16);
      }
#pragma unroll
      for (int i = 0; i < 4; ++i)
#pragma unroll
        for (int j = 0; j < 4; ++j)
          acc[i][j] = __builtin_amdgcn_mfma_f32_16x16x32_bf16(av[i], bv[j], acc[i][j], 0, 0, 0);
    }
    __syncthreads();
  }

  const int row0 = m0 + wm * 64, col0 = n0 + wn * 64;
#pragma unroll
  for (int i = 0; i < 4; ++i)
#pragma unroll
    for (int j = 0; j < 4; ++j)
#pragma unroll
      for (int r = 0; r < 4; ++r) {
        int row = row0 + i * 16 + lk * 4 + r;
        int col = col0 + j * 16 + lrow;
        float v = acc[i][j][r];
        if (col < DINNER) Cb[(size_t)row * DINNER + col] = f2bf(v);
        else if (col < DINNER + CONVD) Cb2[(size_t)row * CONVD + (col - DINNER)] = f2bf(v);
      }
}

// ---------------- 8-wave 256x128 pipelined bf16 GEMM (2-phase/K-tile) ------
// EPI 1: vv=v*invr[row]; t=vv*rsqrt(1+vv^2)->bf16   EPI 2: v+bias+resid->f32
template <int EPI>
__global__ __launch_bounds__(512)
void gemm8p(const short* __restrict__ A, const short* __restrict__ B,
            int K, int nTilesN, int N_out,
            float* __restrict__ Cf, short* __restrict__ Cb,
            const float* __restrict__ bias, const float* __restrict__ resid,
            const float* __restrict__ invr) {
  __shared__ alignas(16) char lds[147456];  // 3 slots x 48KB
  const int tid = threadIdx.x;
  int bid = blockIdx.x;
  {
    int nwg = gridDim.x;
    if ((nwg & 7) == 0) bid = (bid & 7) * (nwg >> 3) + (bid >> 3);
  }
  const int m0 = (bid / nTilesN) * 256;
  const int n0 = (bid % nTilesN) * 128;
  const int lane = tid & 63;
  const int wid = tid >> 6;
  const int wm = wid >> 1;
  const int wn = wid & 1;
  const int lrow = lane & 15, lk = lane >> 4;
  const int nK = K >> 6;

#define LDSA(s) (lds + (s) * 49152)
#define LDSB(s) (lds + (s) * 49152 + 32768)

#define STAGE_A(s, kt, it) do {                                              \
    int p_ = (it) * 8192 + tid * 16;                                         \
    int row_ = p_ >> 7, c_ = p_ & 127;                                       \
    int sc_ = c_ ^ ((row_ & 7) << 4);                                        \
    gload_lds16((const char*)A + ((size_t)(m0 + row_) * K + (kt) * 64) * 2 + sc_, \
                LDSA(s) + p_);                                               \
  } while (0)
#define STAGE_B(s, kt, it) do {                                              \
    int p_ = (it) * 8192 + tid * 16;                                         \
    int row_ = p_ >> 7, c_ = p_ & 127;                                       \
    int sc_ = c_ ^ ((row_ & 7) << 4);                                        \
    gload_lds16((const char*)B + ((size_t)(n0 + row_) * K + (kt) * 64) * 2 + sc_, \
                LDSB(s) + p_);                                               \
  } while (0)

  f32x4 acc[4][4];
#pragma unroll
  for (int i = 0; i < 4; ++i)
#pragma unroll
    for (int j = 0; j < 4; ++j) acc[i][j] = (f32x4)0.f;

#pragma unroll
  for (int it = 0; it < 4; ++it) STAGE_A(0, 0, it);
#pragma unroll
  for (int it = 0; it < 2; ++it) STAGE_B(0, 0, it);
#pragma unroll
  for (int it = 0; it < 4; ++it) STAGE_A(1, 1, it);
#pragma unroll
  for (int it = 0; it < 2; ++it) STAGE_B(1, 1, it);
  asm volatile("s_waitcnt vmcnt(6)" ::: "memory");
  __builtin_amdgcn_s_barrier();

  for (int kt = 0; kt < nK; ++kt) {
    const int rs = kt % 3;
    const int ss = (kt + 2) % 3;
    const bool st = (kt + 2) < nK;
    const char* Ab = LDSA(rs);
    const char* Bb = LDSB(rs);
    short8 aF[4][2], bF[4][2];

#pragma unroll
    for (int ii = 0; ii < 4; ++ii)
#pragma unroll
      for (int ks = 0; ks < 2; ++ks)
        aF[ii][ks] = fragr(Ab, wm * 64 + ii * 16 + lrow, ks * 64 + lk * 16);
#pragma unroll
    for (int jj = 0; jj < 2; ++jj)
#pragma unroll
      for (int ks = 0; ks < 2; ++ks)
        bF[jj][ks] = fragr(Bb, wn * 64 + jj * 16 + lrow, ks * 64 + lk * 16);
    if (st) { STAGE_A(ss, kt + 2, 0); STAGE_A(ss, kt + 2, 1); STAGE_A(ss, kt + 2, 2); STAGE_A(ss, kt + 2, 3); }
    __builtin_amdgcn_s_barrier();
    asm volatile("s_waitcnt lgkmcnt(0)" ::: "memory");
    __builtin_amdgcn_s_setprio(1);
#pragma unroll
    for (int ii = 0; ii < 4; ++ii)
#pragma unroll
      for (int jj = 0; jj < 2; ++jj)
#pragma unroll
        for (int ks = 0; ks < 2; ++ks)
          acc[ii][jj] = __builtin_amdgcn_mfma_f32_16x16x32_bf16(aF[ii][ks], bF[jj][ks], acc[ii][jj], 0, 0, 0);
    __builtin_amdgcn_s_setprio(0);
    __builtin_amdgcn_s_barrier();

#pragma unroll
    for (int jj = 2; jj < 4; ++jj)
#pragma unroll
      for (int ks = 0; ks < 2; ++ks)
        bF[jj][ks] = fragr(Bb, wn * 64 + jj * 16 + lrow, ks * 64 + lk * 16);
    if (st) { STAGE_B(ss, kt + 2, 0); STAGE_B(ss, kt + 2, 1); }
    __builtin_amdgcn_s_barrier();
    asm volatile("s_waitcnt lgkmcnt(0)" ::: "memory");
    __builtin_amdgcn_s_setprio(1);
#pragma unroll
    for (int ii = 0; ii < 4; ++ii)
#pragma unroll
      for (int jj = 2; jj < 4; ++jj)
#pragma unroll
        for (int ks = 0; ks < 2; ++ks)
          acc[ii][jj] = __builtin_amdgcn_mfma_f32_16x16x32_bf16(aF[ii][ks], bF[jj][ks], acc[ii][jj], 0, 0, 0);
    __builtin_amdgcn_s_setprio(0);
    if (kt >= nK - 2) {
      asm volatile("s_waitcnt vmcnt(0)" ::: "memory");
    } else {
      asm volatile("s_waitcnt vmcnt(6)" ::: "memory");
    }
    __builtin_amdgcn_s_barrier();
  }

  const int row0 = m0 + wm * 64, col0 = n0 + wn * 64;
#pragma unroll
  for (int i = 0; i < 4; ++i)
#pragma unroll
    for (int j = 0; j < 4; ++j)
#pragma unroll
      for (int r = 0; r < 4; ++r) {
        int row = row0 + i * 16 + lk * 4 + r;
        int col = col0 + j * 16 + lrow;
        float v = acc[i][j][r];
        if (EPI == 1) {
          float vv = v * invr[row];
          float t = vv * rsqrtf(1.f + vv * vv);
          Cb[(size_t)row * N_out + col] = f2bf(t);
        } else if (EPI == 2) {
          Cf[(size_t)row * N_out + col] = v + bias[col] + resid[(size_t)row * N_out + col];
        }
      }
#undef LDSA
#undef LDSB
#undef STAGE_A
#undef STAGE_B
}

// ---------------- depthwise causal conv16 + SiLU, register-blocked ----------
__global__ __launch_bounds__(256) void conv_silu_kernel(const short* __restrict__ xbcpre,
                                                        const float* __restrict__ cw,
                                                        const float* __restrict__ cbias,
                                                        short* __restrict__ bc,
                                                        short* __restrict__ xT,
                                                        short* __restrict__ bTg) {
  __shared__ short tld[64][130];   // [t][128 ch + 2 pad]
  int blk = blockIdx.x;            // 17*32*4
  int cg = blk % 17;
  int tg = (blk / 17) % 32;
  int b  = blk / (17 * 32);
  int lane = threadIdx.x & 63;
  int warp = threadIdx.x >> 6;
  int c0 = cg * 128 + lane * 2;
  int tbase = (tg * 4 + warp) * TT;

  const short* inp = xbcpre + (size_t)(b * SEQLEN) * CONVD + c0;
  uint32_t in[TT + DCONV - 1];
#pragma unroll
  for (int j = 0; j < TT + DCONV - 1; ++j) {
    int t = tbase + j - (DCONV - 1);
    in[j] = (t >= 0) ? *(const uint32_t*)(inp + (size_t)t * CONVD) : 0u;
  }
  float w0[DCONV], w1[DCONV];
  const float* wp = cw + (size_t)c0 * DCONV;
#pragma unroll
  for (int k = 0; k < DCONV; ++k) { w0[k] = wp[k]; w1[k] = wp[DCONV + k]; }
  float bb0 = cbias[c0], bb1 = cbias[c0 + 1];

  const bool isBC = (cg == 16);
  short* bcp = bc + (size_t)(b * SEQLEN) * 128 + (c0 - DINNER);
#pragma unroll
  for (int tt = 0; tt < TT; ++tt) {
    float a0 = bb0, a1 = bb1;
#pragma unroll
    for (int k = 0; k < DCONV; ++k) {
      uint32_t v = in[tt + k];
      a0 = fmaf(bf2f((short)(v & 0xffffu)), w0[k], a0);
      a1 = fmaf(bf2f((short)(v >> 16)), w1[k], a1);
    }
    a0 = a0 * sigmoidf_fast(a0);
    a1 = a1 * sigmoidf_fast(a1);
    uint32_t o = (uint32_t)(uint16_t)f2bf(a0) | ((uint32_t)(uint16_t)f2bf(a1) << 16);
    if (isBC) *(uint32_t*)(bcp + (size_t)(tbase + tt) * 128) = o;
    *(uint32_t*)&tld[warp * TT + tt][lane * 2] = o;
  }
  __syncthreads();
  int ch = threadIdx.x & 127;
  int seg = threadIdx.x >> 7;
  int gc = cg * 128 + ch;
  short* dst = nullptr;
  if (gc < DINNER) dst = xT + (size_t)gc * ROWS;
  else if (gc < DINNER + NS) dst = bTg + (size_t)(gc - DINNER) * ROWS;
  if (dst) {
    int tcol = b * SEQLEN + tg * 64 + seg * 32;
    short8 v[4];
#pragma unroll
    for (int q = 0; q < 4; ++q)
#pragma unroll
      for (int j = 0; j < 8; ++j) v[q][j] = tld[seg * 32 + q * 8 + j][ch];
    short8* dp = (short8*)(dst + tcol);
    dp[0] = v[0]; dp[1] = v[1]; dp[2] = v[2]; dp[3] = v[3];
  }
}

// ---------------- scan pass A (MFMA, p-split x2): chunk state contribution --
__global__ __launch_bounds__(256)
void scan_passA_mfma(const short* __restrict__ xT, const short* __restrict__ bTg,
                     const float* __restrict__ dtg, const float* __restrict__ ldA,
                     float* __restrict__ Sg, float* __restrict__ Pg) {
  __shared__ alignas(16) char Ax[16384];   // [128p][64s]
  __shared__ alignas(16) char Bt[8192];    // [64n][64s]
  __shared__ float aa[QC + 1];
  __shared__ float wdt[QC];
  __shared__ float wsum[4];
  int blk2 = blockIdx.x;                   // 512 blocks: (blk, half)
  {  // XCD-chunked swizzle: consecutive (blk,half) pairs share panels
    int nwg = gridDim.x;
    if ((nwg & 7) == 0) blk2 = (blk2 & 7) * (nwg >> 3) + (blk2 >> 3);
  }
  int half = blk2 & 1, blk = blk2 >> 1;
  int c8 = blk & 7, bh = blk >> 3;
  int h = bh & 7, b = bh >> 3;
  int pbase = half * 128;
  int tid = threadIdx.x, wave = tid >> 6, lane = tid & 63;
  int lrow = lane & 15, lk = lane >> 4;
  int rowbase = b * SEQLEN + c8 * QC;
  prefix_aa(ldA[(rowbase + tid) * NH + h], aa, wsum, tid);
  float alast = aa[QC];
  if (tid == 0 && half == 0) Pg[blk] = __expf(alast);
  wdt[tid] = __expf(alast - aa[tid + 1]) * dtg[(rowbase + tid) * NH + h];

  f32x4 acc[2][4];
#pragma unroll
  for (int i = 0; i < 2; ++i)
#pragma unroll
    for (int j = 0; j < 4; ++j) acc[i][j] = (f32x4)0.f;

  for (int ks = 0; ks < 4; ++ks) {
    int s0 = ks * 64;
#pragma unroll
    for (int it = 0; it < 4; ++it) {     // 128 rows x 128B
      int p = it * 4096 + tid * 16;
      int row = p >> 7, c = p & 127;
      int sc = c ^ ((row & 7) << 4);
      gload_lds16((const char*)(xT + (size_t)(h * HD + pbase + row) * ROWS + rowbase + s0) + sc, Ax + p);
    }
#pragma unroll
    for (int it = 0; it < 2; ++it) {
      int p = it * 4096 + tid * 16;
      int row = p >> 7, c = p & 127;
      int sc = c ^ ((row & 7) << 4);
      gload_lds16((const char*)(bTg + (size_t)row * ROWS + rowbase + s0) + sc, Bt + p);
    }
    asm volatile("s_waitcnt vmcnt(0)" ::: "memory");
    __syncthreads();
    {  // wave-local scale
      int row = wave * 32 + (lane & 31);
      int gb = (lane >> 5) * 4;
#pragma unroll
      for (int gi = 0; gi < 4; ++gi) {
        int g = gb + gi;
        int off = row * 128 + g * 16;
        int sb = s0 + (((g * 16) ^ ((row & 7) << 4)) >> 1);
        short8 v = *(short8*)(Ax + off);
        short8 o;
#pragma unroll
        for (int j = 0; j < 8; ++j) o[j] = f2bf(bf2f(v[j]) * wdt[sb + j]);
        *(short8*)(Ax + off) = o;
      }
    }
    __syncthreads();
#pragma unroll
    for (int kk = 0; kk < 2; ++kk) {
      short8 av[2], bv[4];
#pragma unroll
      for (int i = 0; i < 2; ++i)
        av[i] = fragr(Ax, wave * 32 + i * 16 + lrow, kk * 64 + lk * 16);
#pragma unroll
      for (int j = 0; j < 4; ++j)
        bv[j] = fragr(Bt, j * 16 + lrow, kk * 64 + lk * 16);
#pragma unroll
      for (int i = 0; i < 2; ++i)
#pragma unroll
        for (int j = 0; j < 4; ++j)
          acc[i][j] = __builtin_amdgcn_mfma_f32_16x16x32_bf16(av[i], bv[j], acc[i][j], 0, 0, 0);
    }
    __syncthreads();
  }
#pragma unroll
  for (int i = 0; i < 2; ++i)
#pragma unroll
    for (int j = 0; j < 4; ++j)
#pragma unroll
      for (int r = 0; r < 4; ++r) {
        int p = pbase + wave * 32 + i * 16 + lk * 4 + r;
        int n = j * 16 + lrow;
        Sg[((size_t)blk * 256 + p) * 64 + n] = acc[i][j][r];
      }
}

// ---------------- scan pass B: inter-chunk combine ----------
__global__ __launch_bounds__(256)
void scan_passB(const float* __restrict__ Sg, const float* __restrict__ Pg,
                const float* __restrict__ init, float* __restrict__ Hg) {
  int blk = blockIdx.x;
  int ptile = blk & 15, bh = blk >> 4;
  int h = bh & (NH - 1);
  int tid = threadIdx.x;
  size_t off = (size_t)ptile * 1024 + tid * 4;
  f32x4 hc = *(const f32x4*)(init + (size_t)h * HD * NS + off);
#pragma unroll 1
  for (int c = 0; c < NC; ++c) {
    *(f32x4*)(Hg + (size_t)(bh * NC + c) * 16384 + off) = hc;
    float P = Pg[bh * NC + c];
    f32x4 s = *(const f32x4*)(Sg + (size_t)(bh * NC + c) * 16384 + off);
    hc = P * hc + s;
  }
}

// ---------------- scan pass C (MFMA, p-split x2): chunked y + fused gate ----
__global__ __launch_bounds__(256)
void scan_passC_mfma(const short* __restrict__ xT, const short* __restrict__ bTg,
                     const short* __restrict__ bc, const short* __restrict__ zb,
                     const float* __restrict__ dtg, const float* __restrict__ ldA,
                     const float* __restrict__ Hg, const float* __restrict__ Dp,
                     float* __restrict__ psum, short* __restrict__ yfull) {
  __shared__ alignas(16) char Xb[16384];   // [128p][64s]
  __shared__ alignas(16) char Hb[16384];   // [128p][64n]
  __shared__ alignas(16) char Bn[8192];    // [64s][64n]
  __shared__ alignas(16) char Cn[8192];    // [64t][64n]
  __shared__ alignas(16) char Bt2[8192];   // [64n][64s]
  __shared__ alignas(16) char Mm[8192];    // [64t][64s]
  __shared__ float aa[QC + 1];
  __shared__ float dts[QC];
  __shared__ float wsum[4];
  int blk2 = blockIdx.x;                   // 512 blocks
  {  // XCD-chunked swizzle
    int nwg = gridDim.x;
    if ((nwg & 7) == 0) blk2 = (blk2 & 7) * (nwg >> 3) + (blk2 >> 3);
  }
  int half = blk2 & 1, blk = blk2 >> 1;
  int c8 = blk & 7, bh = blk >> 3;
  int h = bh & 7, b = bh >> 3;
  int pbase = half * 128;
  int tid = threadIdx.x, wave = tid >> 6, lane = tid & 63;
  int lrow = lane & 15, lk = lane >> 4;
  int rowbase = b * SEQLEN + c8 * QC;
  prefix_aa(ldA[(rowbase + tid) * NH + h], aa, wsum, tid);
  dts[tid] = dtg[(rowbase + tid) * NH + h];
  __syncthreads();
  float Dh = Dp[h];
  const int slot = (h * 2 + half) * 4 + wave;

  f32x4 hcc[2][4];
  const float* hp = Hg + (size_t)blk * 16384;
#pragma unroll
  for (int i = 0; i < 2; ++i)
#pragma unroll
    for (int j = 0; j < 4; ++j)
#pragma unroll
      for (int r = 0; r < 4; ++r)
        hcc[i][j][r] = hp[(size_t)(pbase + wave * 32 + i * 16 + lk * 4 + r) * 64 + j * 16 + lrow];

  for (int sc = 0; sc < 4; ++sc) {
    int s0 = sc * SC;
    // h -> Hb bf16 (wave-local rows)
#pragma unroll
    for (int i = 0; i < 2; ++i)
#pragma unroll
      for (int j = 0; j < 4; ++j)
#pragma unroll
        for (int r = 0; r < 4; ++r) {
          int pl = wave * 32 + i * 16 + lk * 4 + r;
          int n = j * 16 + lrow;
          *(short*)(Hb + pl * 128 + ((n * 2) ^ ((pl & 7) << 4))) = f2bf(hcc[i][j][r]);
        }
#pragma unroll
    for (int it = 0; it < 4; ++it) {     // Xb: 128 rows
      int p = it * 4096 + tid * 16;
      int row = p >> 7, c = p & 127;
      int scz = c ^ ((row & 7) << 4);
      gload_lds16((const char*)(xT + (size_t)(h * HD + pbase + row) * ROWS + rowbase + s0) + scz, Xb + p);
    }
#pragma unroll
    for (int it = 0; it < 2; ++it) {
      int p = it * 4096 + tid * 16;
      int row = p >> 7, c = p & 127;
      int scz = c ^ ((row & 7) << 4);
      gload_lds16((const char*)(bc + (size_t)(rowbase + s0 + row) * 128) + scz, Bn + p);
      gload_lds16((const char*)(bc + (size_t)(rowbase + s0 + row) * 128 + NS) + scz, Cn + p);
      gload_lds16((const char*)(bTg + (size_t)row * ROWS + rowbase + s0) + scz, Bt2 + p);
    }
    asm volatile("s_waitcnt vmcnt(0)" ::: "memory");
    __syncthreads();  // S1

    // G = C * B^T (wave owns t-rows [16w,16w+16))
    f32x4 gcc[4];
#pragma unroll
    for (int j = 0; j < 4; ++j) gcc[j] = (f32x4)0.f;
#pragma unroll
    for (int kk = 0; kk < 2; ++kk) {
      short8 avc = fragr(Cn, wave * 16 + lrow, kk * 64 + lk * 16);
#pragma unroll
      for (int j = 0; j < 4; ++j) {
        short8 bvb = fragr(Bn, j * 16 + lrow, kk * 64 + lk * 16);
        gcc[j] = __builtin_amdgcn_mfma_f32_16x16x32_bf16(avc, bvb, gcc[j], 0, 0, 0);
      }
    }
#pragma unroll
    for (int j = 0; j < 4; ++j)
#pragma unroll
      for (int r = 0; r < 4; ++r) {
        int t = wave * 16 + lk * 4 + r;
        int s = j * 16 + lrow;
        float val = (s <= t) ? gcc[j][r] * __expf(aa[s0 + t + 1] - aa[s0 + s + 1]) * dts[s0 + s]
                             : 0.f;
        *(short*)(Mm + t * 128 + ((s * 2) ^ ((t & 7) << 4))) = f2bf(val);
      }
#pragma unroll
    for (int pass = 0; pass < 2; ++pass) {
      int t = wave * 16 + (lane >> 3) + pass * 8;
      int g = lane & 7;
      int off = t * 128 + g * 16;
      float fac = __expf(aa[s0 + t + 1] - aa[s0]);
      short8 v = *(short8*)(Cn + off);
      short8 o;
#pragma unroll
      for (int j = 0; j < 8; ++j) o[j] = f2bf(bf2f(v[j]) * fac);
      *(short8*)(Cn + off) = o;
    }
    __syncthreads();  // S2

    // Y = M@X + Ce@h  (ycc[t 4][p 2], wave p-slab = 32 rows)
    f32x4 ycc[4][2];
#pragma unroll
    for (int i = 0; i < 4; ++i)
#pragma unroll
      for (int j = 0; j < 2; ++j) ycc[i][j] = (f32x4)0.f;
#pragma unroll
    for (int kk = 0; kk < 2; ++kk) {
      short8 av[4], bv[2];
#pragma unroll
      for (int i = 0; i < 4; ++i)
        av[i] = fragr(Mm, i * 16 + lrow, kk * 64 + lk * 16);
#pragma unroll
      for (int j = 0; j < 2; ++j)
        bv[j] = fragr(Xb, wave * 32 + j * 16 + lrow, kk * 64 + lk * 16);
#pragma unroll
      for (int i = 0; i < 4; ++i)
#pragma unroll
        for (int j = 0; j < 2; ++j)
          ycc[i][j] = __builtin_amdgcn_mfma_f32_16x16x32_bf16(av[i], bv[j], ycc[i][j], 0, 0, 0);
    }
#pragma unroll
    for (int kk = 0; kk < 2; ++kk) {
      short8 av[4], bv[2];
#pragma unroll
      for (int i = 0; i < 4; ++i)
        av[i] = fragr(Cn, i * 16 + lrow, kk * 64 + lk * 16);
#pragma unroll
      for (int j = 0; j < 2; ++j)
        bv[j] = fragr(Hb, wave * 32 + j * 16 + lrow, kk * 64 + lk * 16);
#pragma unroll
      for (int i = 0; i < 4; ++i)
#pragma unroll
        for (int j = 0; j < 2; ++j)
          ycc[i][j] = __builtin_amdgcn_mfma_f32_16x16x32_bf16(av[i], bv[j], ycc[i][j], 0, 0, 0);
    }
    // epilogue: y -> gate with silu(z) -> yfull(gated) + per-row sumsq partial
#pragma unroll
    for (int i = 0; i < 4; ++i)
#pragma unroll
      for (int r = 0; r < 4; ++r) {
        int t = i * 16 + lk * 4 + r;
        size_t grow = (size_t)(rowbase + s0 + t);
        float pq = 0.f;
#pragma unroll
        for (int j = 0; j < 2; ++j) {
          int pl = wave * 32 + j * 16 + lrow;
          float xv = bf2f(*(const short*)(Xb + pl * 128 + ((t * 2) ^ ((pl & 7) << 4))));
          float yv = ycc[i][j][r] + Dh * xv;
          float zv = bf2f(zb[grow * DINNER + h * HD + pbase + pl]);
          float val = yv * zv * sigmoidf_fast(zv);
          yfull[grow * DINNER + h * HD + pbase + pl] = f2bf(val);
          pq = fmaf(val, val, pq);
        }
#pragma unroll
        for (int m = 1; m < 16; m <<= 1) pq += __shfl_xor(pq, m);
        if (lrow == 0) psum[grow * 64 + slot] = pq;
      }
    {  // scale Xb in place (wave-local rows)
      int row = wave * 32 + (lane & 31);
      int gb = (lane >> 5) * 4;
      float aend = aa[s0 + SC];
#pragma unroll
      for (int gi = 0; gi < 4; ++gi) {
        int g = gb + gi;
        int off = row * 128 + g * 16;
        int sb = s0 + (((g * 16) ^ ((row & 7) << 4)) >> 1);
        short8 v = *(short8*)(Xb + off);
        short8 o;
#pragma unroll
        for (int j = 0; j < 8; ++j)
          o[j] = f2bf(bf2f(v[j]) * __expf(aend - aa[sb + j + 1]) * dts[sb + j]);
        *(short8*)(Xb + off) = o;
      }
    }
    {  // h = P_sub*h + Xw^T @ B
      float Ps = __expf(aa[s0 + SC] - aa[s0]);
#pragma unroll
      for (int i = 0; i < 2; ++i)
#pragma unroll
        for (int j = 0; j < 4; ++j) hcc[i][j] *= Ps;
#pragma unroll
      for (int kk = 0; kk < 2; ++kk) {
        short8 av[2], bv[4];
#pragma unroll
        for (int i = 0; i < 2; ++i)
          av[i] = fragr(Xb, wave * 32 + i * 16 + lrow, kk * 64 + lk * 16);
#pragma unroll
        for (int j = 0; j < 4; ++j)
          bv[j] = fragr(Bt2, j * 16 + lrow, kk * 64 + lk * 16);
#pragma unroll
        for (int i = 0; i < 2; ++i)
#pragma unroll
          for (int j = 0; j < 4; ++j)
            hcc[i][j] = __builtin_amdgcn_mfma_f32_16x16x32_bf16(av[i], bv[j], hcc[i][j], 0, 0, 0);
      }
    }
    __syncthreads();  // S3
  }
}

// ---------------- invrms: reduce psum[8192][64] -> invr[8192] ----------------
__global__ __launch_bounds__(256)
void invrms_kernel(const float* __restrict__ psum, float* __restrict__ invr) {
  int row = blockIdx.x * 256 + threadIdx.x;
  const f32x4* p = (const f32x4*)(psum + (size_t)row * 64);
  float s = 0.f;
#pragma unroll
  for (int q = 0; q < 16; ++q) { f32x4 v = p[q]; s += (v[0] + v[1]) + (v[2] + v[3]); }
  invr[row] = rsqrtf(s * (1.f / (float)DINNER) + 1e-5f);
}

// ---------------- launcher ----------------
extern "C" void kernel_launch(void* const* d_in, const int* in_sizes, int n_in,
                              void* d_out, int out_size, void* d_ws, size_t ws_size,
                              hipStream_t stream) {
  (void)in_sizes; (void)n_in; (void)out_size; (void)ws_size;
  const float* x     = (const float*)d_in[0];
  const float* W_in  = (const float*)d_in[1];
  const float* convw = (const float*)d_in[2];
  const float* convb = (const float*)d_in[3];
  const float* dtb   = (const float*)d_in[4];
  const float* Alog  = (const float*)d_in[5];
  const float* Dp    = (const float*)d_in[6];
  const float* inis  = (const float*)d_in[7];
  const float* nw    = (const float*)d_in[8];
  const float* W_out = (const float*)d_in[9];
  const float* W_nl  = (const float*)d_in[10];
  const float* b_nl  = (const float*)d_in[11];
  float* out = (float*)d_out;
  char* ws = (char*)d_ws;

  short* woutT  = (short*)(ws + O_WOUT);
  short* wnlT   = (short*)(ws + O_WNL);
  float* dtg    = (float*)(ws + O_DT);
  float* ldA    = (float*)(ws + O_LDA);
  float* Pg     = (float*)(ws + O_PG);
  short* bTg    = (short*)(ws + O_BT);
  short* zb     = (short*)(ws + O_ZB);
  short* xbcpre = (short*)(ws + O_XBCPRE);
  float* Sg     = (float*)(ws + O_SG);
  float* Hg     = (float*)(ws + O_HG);
  short* tb     = (short*)(ws + O_TB);
  short* bc     = (short*)(ws + O_XBC);
  short* xT     = (short*)(ws + O_XTR);
  short* xbf    = (short*)(ws + O_XBF);
  short* winT   = (short*)(ws + O_WIN);
  float* wtailT = (float*)(ws + O_WTAIL);
  float* psum   = (float*)(ws + O_PSUM);
  float* invr   = (float*)(ws + O_INVR);
  short* yfull  = (short*)d_out;

  prep_weights_kernel<<<1856, 256, 0, stream>>>(W_in, W_out, W_nl, nw, winT, woutT, wnlT, wtailT);
  cast_dt_kernel<<<ROWS, 256, 0, stream>>>(x, wtailT, dtb, Alog, xbf, dtg, ldA);

  // GEMM1: M=8192 (32 tiles of 256), N=4224 (33 tiles of 128), K=1024 -> 1056 blocks
  gemm1_256<<<32 * 33, 512, 0, stream>>>(xbf, winT, HM, 33, zb, xbcpre);
  conv_silu_kernel<<<17 * 32 * 4, 256, 0, stream>>>(xbcpre, convw, convb, bc, xT, bTg);

  scan_passA_mfma<<<32 * NC * 2, 256, 0, stream>>>(xT, bTg, dtg, ldA, Sg, Pg);
  scan_passB<<<32 * 16, 256, 0, stream>>>(Sg, Pg, inis, Hg);
  scan_passC_mfma<<<32 * NC * 2, 256, 0, stream>>>(xT, bTg, bc, zb, dtg, ldA, Hg, Dp, psum, yfull);

  invrms_kernel<<<32, 256, 0, stream>>>(psum, invr);
  // GEMM2: A = gated yfull (d_out bf16), woutT pre-scaled by norm_w; invr in epilogue
  gemm8p<1><<<32 * 8, 512, 0, stream>>>(yfull, woutT, DINNER, 8, HM, nullptr, tb, nullptr, nullptr, invr);
  // GEMM3: M=8192, N=1024, K=1024 -> 256 blocks
  gemm8p<2><<<32 * 8, 512, 0, stream>>>(tb, wnlT, HM, 8, HM, out, nullptr, b_nl, x, nullptr);
}

// Round 15
// 290.620 us; speedup vs baseline: 1.0469x; 1.0469x over previous
//
#include <hip/hip_runtime.h>
#include <stdint.h>
#include <stddef.h>

// ---------------- problem dims ----------------
#define BATCH   4
#define SEQLEN  2048
#define HM      1024
#define DINNER  2048
#define NH      8
#define HD      256
#define NS      64
#define CONVD   2176
#define DCONV   16
#define DPROJ   4232
#define ROWS    (BATCH*SEQLEN)  // 8192
#define QC      256             // big-chunk length
#define NC      (SEQLEN/QC)     // 8 big-chunks
#define SC      64              // sub-chunk length (passC)
#define TT      16              // conv timesteps per thread

typedef __attribute__((ext_vector_type(8))) short short8;
typedef __attribute__((ext_vector_type(4))) short short4v;
typedef __attribute__((ext_vector_type(4))) float f32x4;

// ---------------- workspace layout (bytes) ----------------
static constexpr size_t O_WOUT   = 0;                    //  4,194,304
static constexpr size_t O_WNL    = 4194304;              //  2,097,152
static constexpr size_t O_DT     = 6291456;              //    262,144
static constexpr size_t O_LDA    = 6553600;              //    262,144
static constexpr size_t O_PG     = 6815744;              //      4,096
static constexpr size_t O_BT     = 6819840;              //  1,048,576
static constexpr size_t O_ZB     = 7868416;              // 33,554,432  bf16 z[8192][2048]
static constexpr size_t O_XBCPRE = 41422848;             // 35,651,584  bf16 [8192][2176]
static constexpr size_t O_SG     = O_XBCPRE;             // 16,777,216  f32 [65536][64]
static constexpr size_t O_HG     = O_XBCPRE + 16777216;  // 16,777,216  f32 [256][16384]
static constexpr size_t O_TB     = O_XBCPRE;             // 16,777,216  bf16 [8192][1024]
static constexpr size_t O_XBC    = 77074432;             // bc[8192][128] bf16 (2MB); later yn[8192][2048]
static constexpr size_t O_YN     = O_XBC;
static constexpr size_t O_XTR    = 112726016;            // 33,554,432  bf16 xT[2048][8192]
static constexpr size_t O_XBF    = O_XTR;                // 16,777,216  bf16 [8192][1024]
static constexpr size_t O_WIN    = O_XTR + 16777216;     //  8,912,896  bf16 [4352][1024]
static constexpr size_t O_WTAIL  = 146280448;            //     32,768  f32 wtailT[8][1024]
// END = 146,313,216

// ---------------- helpers ----------------
__device__ __forceinline__ short f2bf(float f) {
  union { float f; uint32_t u; } v; v.f = f;
  uint32_t r = v.u + 0x7fffu + ((v.u >> 16) & 1u);
  return (short)(r >> 16);
}

__device__ __forceinline__ float bf2f(short s) {
  union { float f; uint32_t u; } v;
  v.u = ((uint32_t)(uint16_t)s) << 16;
  return v.f;
}

__device__ __forceinline__ void gload_lds16(const void* g, void* l) {
  __builtin_amdgcn_global_load_lds(
      (const __attribute__((address_space(1))) uint32_t*)g,
      (__attribute__((address_space(3))) uint32_t*)l, 16, 0, 0);
}

__device__ __forceinline__ float sigmoidf_fast(float x) {
  return 1.f / (1.f + __expf(-x));
}

// fragment read from a [rows][64-elem] bf16 LDS tile (128B rows, XOR-swizzled)
__device__ __forceinline__ short8 fragr(const char* base, int row, int kbyte) {
  return *(const short8*)(base + row * 128 + (kbyte ^ ((row & 7) << 4)));
}

// ---------------- combined weight prep: 3 transposes + wtail ----------------
__device__ __forceinline__ void transpose_tile(const float* __restrict__ W,
                                               short* __restrict__ Wt,
                                               int idx, int srcN, int validN,
                                               int Kdim, int nTilesN, int tid) {
  __shared__ short lds[64][72];
  int k0 = (idx / nTilesN) * 64;
  int n0 = (idx % nTilesN) * 64;
  int rr = tid >> 4;
  int cc = (tid & 15) * 4;
#pragma unroll
  for (int pass = 0; pass < 4; ++pass) {
    int k = pass * 16 + rr;
    int gn = n0 + cc;
    f32x4 v = (f32x4)0.f;
    if (gn < validN) v = *(const f32x4*)(W + (size_t)(k0 + k) * srcN + gn);
    uint32_t p0 = (uint32_t)(uint16_t)f2bf(v[0]) | ((uint32_t)(uint16_t)f2bf(v[1]) << 16);
    uint32_t p1 = (uint32_t)(uint16_t)f2bf(v[2]) | ((uint32_t)(uint16_t)f2bf(v[3]) << 16);
    *(uint32_t*)&lds[k][cc] = p0;
    *(uint32_t*)&lds[k][cc + 2] = p1;
  }
  __syncthreads();
  int n = tid >> 2;
  int ks = (tid & 3) * 16;
  short8 a, b;
#pragma unroll
  for (int j = 0; j < 8; ++j) a[j] = lds[ks + j][n];
#pragma unroll
  for (int j = 0; j < 8; ++j) b[j] = lds[ks + 8 + j][n];
  short* dst = Wt + (size_t)(n0 + n) * Kdim + k0 + ks;
  *(short8*)dst = a;
  *(short8*)(dst + 8) = b;
}

__global__ __launch_bounds__(256)
void prep_weights_kernel(const float* __restrict__ W_in, const float* __restrict__ W_out,
                         const float* __restrict__ W_nl,
                         short* __restrict__ winT, short* __restrict__ woutT,
                         short* __restrict__ wnlT, float* __restrict__ wtailT) {
  int bid = blockIdx.x, tid = threadIdx.x;
  if (bid < 1056) {           // W_in^T: 16 k-tiles x 66 n-tiles (n<4224 only)
    transpose_tile(W_in, winT, bid, DPROJ, DPROJ, HM, 66, tid);
  } else if (bid < 1568) {    // W_out^T: 32 k-tiles x 16 n-tiles
    transpose_tile(W_out, woutT, bid - 1056, HM, HM, DINNER, 16, tid);
  } else if (bid < 1824) {    // W_nl^T: 16 x 16
    transpose_tile(W_nl, wnlT, bid - 1568, HM, HM, HM, 16, tid);
  } else {                    // wtail: wtailT[h][k] = W_in[k][4224+h]
    int i = (bid - 1824) * 256 + tid;  // 8192 elems
    int h = i >> 10, k = i & 1023;
    wtailT[i] = W_in[(size_t)k * DPROJ + (DPROJ - NH) + h];
  }
}

// ---------------- fused cast x -> bf16 + dt (exact f32 path) ----------------
__global__ __launch_bounds__(256)
void cast_dt_kernel(const float* __restrict__ x, const float* __restrict__ wtailT,
                    const float* __restrict__ dt_bias, const float* __restrict__ A_log,
                    short* __restrict__ xbf, float* __restrict__ dtg,
                    float* __restrict__ ldA) {
  int row = blockIdx.x, tid = threadIdx.x;
  f32x4 xv = ((const f32x4*)(x + (size_t)row * HM))[tid];
  short4v o = { f2bf(xv[0]), f2bf(xv[1]), f2bf(xv[2]), f2bf(xv[3]) };
  ((short4v*)(xbf + (size_t)row * HM))[tid] = o;
  float p[NH];
#pragma unroll
  for (int h = 0; h < NH; ++h) {
    f32x4 w = ((const f32x4*)(wtailT + h * HM))[tid];
    p[h] = xv[0] * w[0] + xv[1] * w[1] + xv[2] * w[2] + xv[3] * w[3];
  }
#pragma unroll
  for (int h = 0; h < NH; ++h)
#pragma unroll
    for (int of = 32; of; of >>= 1) p[h] += __shfl_down(p[h], of);
  __shared__ float red[4][NH];
  int lane = tid & 63, w4 = tid >> 6;
  if (lane == 0)
#pragma unroll
    for (int h = 0; h < NH; ++h) red[w4][h] = p[h];
  __syncthreads();
  if (tid < NH) {
    float s = red[0][tid] + red[1][tid] + red[2][tid] + red[3][tid] + dt_bias[tid];
    float dtv = (s > 20.f) ? s : log1pf(expf(s));
    float A = -expf(A_log[tid]);
    dtg[row * NH + tid] = dtv;
    ldA[row * NH + tid] = dtv * A;
  }
}

// ---------------- parallel inclusive prefix of ldA into aa[257] ------------
__device__ __forceinline__ void prefix_aa(float av, float* aa, float* wsum,
                                          int tid) {
  float v = av;
  int lane = tid & 63;
#pragma unroll
  for (int o = 1; o < 64; o <<= 1) {
    float u = __shfl_up(v, o);
    if (lane >= o) v += u;
  }
  if (lane == 63) wsum[tid >> 6] = v;
  __syncthreads();
  float off = 0.f;
  int w4 = tid >> 6;
#pragma unroll
  for (int w = 0; w < 4; ++w)
    if (w < w4) off += wsum[w];
  aa[tid + 1] = v + off;
  if (tid == 0) aa[0] = 0.f;
  __syncthreads();
}

// ---------------- GEMM1: 256x128 tile, BK=64, 1-phase, 3 blocks/CU ---------
__global__ __launch_bounds__(512)
void gemm1_256(const short* __restrict__ A, const short* __restrict__ B,
               int K, int nTilesN,
               short* __restrict__ Cb, short* __restrict__ Cb2) {
  __shared__ alignas(16) char lds[49152];
  char* As = lds;           // [256][128B]
  char* Bs = lds + 32768;   // [128][128B]
  const int tid = threadIdx.x;
  int bid = blockIdx.x;
  {
    int nwg = gridDim.x;
    if ((nwg & 7) == 0) bid = (bid & 7) * (nwg >> 3) + (bid >> 3);
  }
  const int m0 = (bid / nTilesN) * 256;
  const int n0 = (bid % nTilesN) * 128;
  const int lane = tid & 63;
  const int wid = tid >> 6;        // 8 waves: 4M x 2N
  const int wm = wid >> 1;
  const int wn = wid & 1;
  const int lrow = lane & 15, lk = lane >> 4;

  f32x4 acc[4][4];
#pragma unroll
  for (int i = 0; i < 4; ++i)
#pragma unroll
    for (int j = 0; j < 4; ++j) acc[i][j] = (f32x4)0.f;

  for (int k0 = 0; k0 < K; k0 += 64) {
#pragma unroll
    for (int r = 0; r < 4; ++r) {  // A: 256 rows x 128B
      int p = r * 8192 + tid * 16;
      int row = p >> 7, c = p & 127;
      int sc = c ^ ((row & 7) << 4);
      gload_lds16((const char*)A + ((size_t)(m0 + row) * K + k0) * 2 + sc, As + p);
    }
#pragma unroll
    for (int r = 0; r < 2; ++r) {  // B: 128 rows x 128B
      int p = r * 8192 + tid * 16;
      int row = p >> 7, c = p & 127;
      int sc = c ^ ((row & 7) << 4);
      gload_lds16((const char*)B + ((size_t)(n0 + row) * K + k0) * 2 + sc, Bs + p);
    }
    asm volatile("s_waitcnt vmcnt(0)" ::: "memory");
    __syncthreads();
#pragma unroll
    for (int ks = 0; ks < 2; ++ks) {
      short8 av[4], bv[4];
#pragma unroll
      for (int i = 0; i < 4; ++i) {
        av[i] = fragr(As, wm * 64 + i * 16 + lrow, ks * 64 + lk * 16);
        bv[i] = fragr(Bs, wn * 64 + i * 16 + lrow, ks * 64 + lk * 16);
      }
#pragma unroll
      for (int i = 0; i < 4; ++i)
#pragma unroll
        for (int j = 0; j < 4; ++j)
          acc[i][j] = __builtin_amdgcn_mfma_f32_16x16x32_bf16(av[i], bv[j], acc[i][j], 0, 0, 0);
    }
    __syncthreads();
  }

  const int row0 = m0 + wm * 64, col0 = n0 + wn * 64;
#pragma unroll
  for (int i = 0; i < 4; ++i)
#pragma unroll
    for (int j = 0; j < 4; ++j)
#pragma unroll
      for (int r = 0; r < 4; ++r) {
        int row = row0 + i * 16 + lk * 4 + r;
        int col = col0 + j * 16 + lrow;
        float v = acc[i][j][r];
        if (col < DINNER) Cb[(size_t)row * DINNER + col] = f2bf(v);
        else if (col < DINNER + CONVD) Cb2[(size_t)row * CONVD + (col - DINNER)] = f2bf(v);
      }
}

// ---------------- 8-wave 256x128 pipelined bf16 GEMM (2-phase/K-tile) ------
template <int EPI>
__global__ __launch_bounds__(512)
void gemm8p(const short* __restrict__ A, const short* __restrict__ B,
            int K, int nTilesN, int N_out,
            float* __restrict__ Cf, short* __restrict__ Cb,
            const float* __restrict__ bias, const float* __restrict__ resid) {
  __shared__ alignas(16) char lds[147456];  // 3 slots x 48KB
  const int tid = threadIdx.x;
  int bid = blockIdx.x;
  {
    int nwg = gridDim.x;
    if ((nwg & 7) == 0) bid = (bid & 7) * (nwg >> 3) + (bid >> 3);
  }
  const int m0 = (bid / nTilesN) * 256;
  const int n0 = (bid % nTilesN) * 128;
  const int lane = tid & 63;
  const int wid = tid >> 6;
  const int wm = wid >> 1;
  const int wn = wid & 1;
  const int lrow = lane & 15, lk = lane >> 4;
  const int nK = K >> 6;

#define LDSA(s) (lds + (s) * 49152)
#define LDSB(s) (lds + (s) * 49152 + 32768)

#define STAGE_A(s, kt, it) do {                                              \
    int p_ = (it) * 8192 + tid * 16;                                         \
    int row_ = p_ >> 7, c_ = p_ & 127;                                       \
    int sc_ = c_ ^ ((row_ & 7) << 4);                                        \
    gload_lds16((const char*)A + ((size_t)(m0 + row_) * K + (kt) * 64) * 2 + sc_, \
                LDSA(s) + p_);                                               \
  } while (0)
#define STAGE_B(s, kt, it) do {                                              \
    int p_ = (it) * 8192 + tid * 16;                                         \
    int row_ = p_ >> 7, c_ = p_ & 127;                                       \
    int sc_ = c_ ^ ((row_ & 7) << 4);                                        \
    gload_lds16((const char*)B + ((size_t)(n0 + row_) * K + (kt) * 64) * 2 + sc_, \
                LDSB(s) + p_);                                               \
  } while (0)

  f32x4 acc[4][4];
#pragma unroll
  for (int i = 0; i < 4; ++i)
#pragma unroll
    for (int j = 0; j < 4; ++j) acc[i][j] = (f32x4)0.f;

#pragma unroll
  for (int it = 0; it < 4; ++it) STAGE_A(0, 0, it);
#pragma unroll
  for (int it = 0; it < 2; ++it) STAGE_B(0, 0, it);
#pragma unroll
  for (int it = 0; it < 4; ++it) STAGE_A(1, 1, it);
#pragma unroll
  for (int it = 0; it < 2; ++it) STAGE_B(1, 1, it);
  asm volatile("s_waitcnt vmcnt(6)" ::: "memory");
  __builtin_amdgcn_s_barrier();

  for (int kt = 0; kt < nK; ++kt) {
    const int rs = kt % 3;
    const int ss = (kt + 2) % 3;
    const bool st = (kt + 2) < nK;
    const char* Ab = LDSA(rs);
    const char* Bb = LDSB(rs);
    short8 aF[4][2], bF[4][2];

#pragma unroll
    for (int ii = 0; ii < 4; ++ii)
#pragma unroll
      for (int ks = 0; ks < 2; ++ks)
        aF[ii][ks] = fragr(Ab, wm * 64 + ii * 16 + lrow, ks * 64 + lk * 16);
#pragma unroll
    for (int jj = 0; jj < 2; ++jj)
#pragma unroll
      for (int ks = 0; ks < 2; ++ks)
        bF[jj][ks] = fragr(Bb, wn * 64 + jj * 16 + lrow, ks * 64 + lk * 16);
    if (st) { STAGE_A(ss, kt + 2, 0); STAGE_A(ss, kt + 2, 1); STAGE_A(ss, kt + 2, 2); STAGE_A(ss, kt + 2, 3); }
    __builtin_amdgcn_s_barrier();
    asm volatile("s_waitcnt lgkmcnt(0)" ::: "memory");
    __builtin_amdgcn_s_setprio(1);
#pragma unroll
    for (int ii = 0; ii < 4; ++ii)
#pragma unroll
      for (int jj = 0; jj < 2; ++jj)
#pragma unroll
        for (int ks = 0; ks < 2; ++ks)
          acc[ii][jj] = __builtin_amdgcn_mfma_f32_16x16x32_bf16(aF[ii][ks], bF[jj][ks], acc[ii][jj], 0, 0, 0);
    __builtin_amdgcn_s_setprio(0);
    __builtin_amdgcn_s_barrier();

#pragma unroll
    for (int jj = 2; jj < 4; ++jj)
#pragma unroll
      for (int ks = 0; ks < 2; ++ks)
        bF[jj][ks] = fragr(Bb, wn * 64 + jj * 16 + lrow, ks * 64 + lk * 16);
    if (st) { STAGE_B(ss, kt + 2, 0); STAGE_B(ss, kt + 2, 1); }
    __builtin_amdgcn_s_barrier();
    asm volatile("s_waitcnt lgkmcnt(0)" ::: "memory");
    __builtin_amdgcn_s_setprio(1);
#pragma unroll
    for (int ii = 0; ii < 4; ++ii)
#pragma unroll
      for (int jj = 2; jj < 4; ++jj)
#pragma unroll
        for (int ks = 0; ks < 2; ++ks)
          acc[ii][jj] = __builtin_amdgcn_mfma_f32_16x16x32_bf16(aF[ii][ks], bF[jj][ks], acc[ii][jj], 0, 0, 0);
    __builtin_amdgcn_s_setprio(0);
    if (kt >= nK - 2) {
      asm volatile("s_waitcnt vmcnt(0)" ::: "memory");
    } else {
      asm volatile("s_waitcnt vmcnt(6)" ::: "memory");
    }
    __builtin_amdgcn_s_barrier();
  }

  const int row0 = m0 + wm * 64, col0 = n0 + wn * 64;
#pragma unroll
  for (int i = 0; i < 4; ++i)
#pragma unroll
    for (int j = 0; j < 4; ++j)
#pragma unroll
      for (int r = 0; r < 4; ++r) {
        int row = row0 + i * 16 + lk * 4 + r;
        int col = col0 + j * 16 + lrow;
        float v = acc[i][j][r];
        if (EPI == 1) {
          float t = v * rsqrtf(1.f + v * v);
          Cb[(size_t)row * N_out + col] = f2bf(t);
        } else if (EPI == 2) {
          Cf[(size_t)row * N_out + col] = v + bias[col] + resid[(size_t)row * N_out + col];
        }
      }
#undef LDSA
#undef LDSB
#undef STAGE_A
#undef STAGE_B
}

// ---------------- depthwise causal conv16 + SiLU, register-blocked ----------
__global__ __launch_bounds__(256) void conv_silu_kernel(const short* __restrict__ xbcpre,
                                                        const float* __restrict__ cw,
                                                        const float* __restrict__ cbias,
                                                        short* __restrict__ bc,
                                                        short* __restrict__ xT,
                                                        short* __restrict__ bTg) {
  __shared__ short tld[64][130];   // [t][128 ch + 2 pad]
  int blk = blockIdx.x;            // 17*32*4
  int cg = blk % 17;
  int tg = (blk / 17) % 32;
  int b  = blk / (17 * 32);
  int lane = threadIdx.x & 63;
  int warp = threadIdx.x >> 6;
  int c0 = cg * 128 + lane * 2;
  int tbase = (tg * 4 + warp) * TT;

  const short* inp = xbcpre + (size_t)(b * SEQLEN) * CONVD + c0;
  uint32_t in[TT + DCONV - 1];
#pragma unroll
  for (int j = 0; j < TT + DCONV - 1; ++j) {
    int t = tbase + j - (DCONV - 1);
    in[j] = (t >= 0) ? *(const uint32_t*)(inp + (size_t)t * CONVD) : 0u;
  }
  float w0[DCONV], w1[DCONV];
  const float* wp = cw + (size_t)c0 * DCONV;
#pragma unroll
  for (int k = 0; k < DCONV; ++k) { w0[k] = wp[k]; w1[k] = wp[DCONV + k]; }
  float bb0 = cbias[c0], bb1 = cbias[c0 + 1];

  const bool isBC = (cg == 16);
  short* bcp = bc + (size_t)(b * SEQLEN) * 128 + (c0 - DINNER);
#pragma unroll
  for (int tt = 0; tt < TT; ++tt) {
    float a0 = bb0, a1 = bb1;
#pragma unroll
    for (int k = 0; k < DCONV; ++k) {
      uint32_t v = in[tt + k];
      a0 = fmaf(bf2f((short)(v & 0xffffu)), w0[k], a0);
      a1 = fmaf(bf2f((short)(v >> 16)), w1[k], a1);
    }
    a0 = a0 * sigmoidf_fast(a0);
    a1 = a1 * sigmoidf_fast(a1);
    uint32_t o = (uint32_t)(uint16_t)f2bf(a0) | ((uint32_t)(uint16_t)f2bf(a1) << 16);
    if (isBC) *(uint32_t*)(bcp + (size_t)(tbase + tt) * 128) = o;
    *(uint32_t*)&tld[warp * TT + tt][lane * 2] = o;
  }
  __syncthreads();
  int ch = threadIdx.x & 127;
  int seg = threadIdx.x >> 7;
  int gc = cg * 128 + ch;
  short* dst = nullptr;
  if (gc < DINNER) dst = xT + (size_t)gc * ROWS;
  else if (gc < DINNER + NS) dst = bTg + (size_t)(gc - DINNER) * ROWS;
  if (dst) {
    int tcol = b * SEQLEN + tg * 64 + seg * 32;
    short8 v[4];
#pragma unroll
    for (int q = 0; q < 4; ++q)
#pragma unroll
      for (int j = 0; j < 8; ++j) v[q][j] = tld[seg * 32 + q * 8 + j][ch];
    short8* dp = (short8*)(dst + tcol);
    dp[0] = v[0]; dp[1] = v[1]; dp[2] = v[2]; dp[3] = v[3];
  }
}

// ---------------- scan pass A (MFMA, p-split x2): chunk state contribution --
__global__ __launch_bounds__(256)
void scan_passA_mfma(const short* __restrict__ xT, const short* __restrict__ bTg,
                     const float* __restrict__ dtg, const float* __restrict__ ldA,
                     float* __restrict__ Sg, float* __restrict__ Pg) {
  __shared__ alignas(16) char Ax[16384];   // [128p][64s]
  __shared__ alignas(16) char Bt[8192];    // [64n][64s]
  __shared__ float aa[QC + 1];
  __shared__ float wdt[QC];
  __shared__ float wsum[4];
  int blk2 = blockIdx.x;                   // 512 blocks: (blk, half)
  int half = blk2 & 1, blk = blk2 >> 1;
  int c8 = blk & 7, bh = blk >> 3;
  int h = bh & 7, b = bh >> 3;
  int pbase = half * 128;
  int tid = threadIdx.x, wave = tid >> 6, lane = tid & 63;
  int lrow = lane & 15, lk = lane >> 4;
  int rowbase = b * SEQLEN + c8 * QC;
  prefix_aa(ldA[(rowbase + tid) * NH + h], aa, wsum, tid);
  float alast = aa[QC];
  if (tid == 0 && half == 0) Pg[blk] = __expf(alast);
  wdt[tid] = __expf(alast - aa[tid + 1]) * dtg[(rowbase + tid) * NH + h];

  f32x4 acc[2][4];
#pragma unroll
  for (int i = 0; i < 2; ++i)
#pragma unroll
    for (int j = 0; j < 4; ++j) acc[i][j] = (f32x4)0.f;

  for (int ks = 0; ks < 4; ++ks) {
    int s0 = ks * 64;
#pragma unroll
    for (int it = 0; it < 4; ++it) {     // 128 rows x 128B
      int p = it * 4096 + tid * 16;
      int row = p >> 7, c = p & 127;
      int sc = c ^ ((row & 7) << 4);
      gload_lds16((const char*)(xT + (size_t)(h * HD + pbase + row) * ROWS + rowbase + s0) + sc, Ax + p);
    }
#pragma unroll
    for (int it = 0; it < 2; ++it) {
      int p = it * 4096 + tid * 16;
      int row = p >> 7, c = p & 127;
      int sc = c ^ ((row & 7) << 4);
      gload_lds16((const char*)(bTg + (size_t)row * ROWS + rowbase + s0) + sc, Bt + p);
    }
    asm volatile("s_waitcnt vmcnt(0)" ::: "memory");
    __syncthreads();
    {  // wave-local scale: wave w scales rows w*32..w*32+31 (granule half by lane>>5)
      int row = wave * 32 + (lane & 31);
      int gb = (lane >> 5) * 4;
#pragma unroll
      for (int gi = 0; gi < 4; ++gi) {
        int g = gb + gi;
        int off = row * 128 + g * 16;
        int sb = s0 + (((g * 16) ^ ((row & 7) << 4)) >> 1);
        short8 v = *(short8*)(Ax + off);
        short8 o;
#pragma unroll
        for (int j = 0; j < 8; ++j) o[j] = f2bf(bf2f(v[j]) * wdt[sb + j]);
        *(short8*)(Ax + off) = o;
      }
    }
    __syncthreads();
#pragma unroll
    for (int kk = 0; kk < 2; ++kk) {
      short8 av[2], bv[4];
#pragma unroll
      for (int i = 0; i < 2; ++i)
        av[i] = fragr(Ax, wave * 32 + i * 16 + lrow, kk * 64 + lk * 16);
#pragma unroll
      for (int j = 0; j < 4; ++j)
        bv[j] = fragr(Bt, j * 16 + lrow, kk * 64 + lk * 16);
#pragma unroll
      for (int i = 0; i < 2; ++i)
#pragma unroll
        for (int j = 0; j < 4; ++j)
          acc[i][j] = __builtin_amdgcn_mfma_f32_16x16x32_bf16(av[i], bv[j], acc[i][j], 0, 0, 0);
    }
    __syncthreads();
  }
#pragma unroll
  for (int i = 0; i < 2; ++i)
#pragma unroll
    for (int j = 0; j < 4; ++j)
#pragma unroll
      for (int r = 0; r < 4; ++r) {
        int p = pbase + wave * 32 + i * 16 + lk * 4 + r;
        int n = j * 16 + lrow;
        Sg[((size_t)blk * 256 + p) * 64 + n] = acc[i][j][r];
      }
}

// ---------------- scan pass B: inter-chunk combine ----------
__global__ __launch_bounds__(256)
void scan_passB(const float* __restrict__ Sg, const float* __restrict__ Pg,
                const float* __restrict__ init, float* __restrict__ Hg) {
  int blk = blockIdx.x;
  int ptile = blk & 15, bh = blk >> 4;
  int h = bh & (NH - 1);
  int tid = threadIdx.x;
  size_t off = (size_t)ptile * 1024 + tid * 4;
  f32x4 hc = *(const f32x4*)(init + (size_t)h * HD * NS + off);
#pragma unroll 1
  for (int c = 0; c < NC; ++c) {
    *(f32x4*)(Hg + (size_t)(bh * NC + c) * 16384 + off) = hc;
    float P = Pg[bh * NC + c];
    f32x4 s = *(const f32x4*)(Sg + (size_t)(bh * NC + c) * 16384 + off);
    hc = P * hc + s;
  }
}

// ---------------- scan pass C (MFMA, p-split x2): chunked y -----------------
__global__ __launch_bounds__(256)
void scan_passC_mfma(const short* __restrict__ xT, const short* __restrict__ bTg,
                     const short* __restrict__ bc,
                     const float* __restrict__ dtg, const float* __restrict__ ldA,
                     const float* __restrict__ Hg, const float* __restrict__ Dp,
                     short* __restrict__ yfull) {
  __shared__ alignas(16) char Xb[16384];   // [128p][64s]
  __shared__ alignas(16) char Hb[16384];   // [128p][64n]
  __shared__ alignas(16) char Bn[8192];    // [64s][64n]
  __shared__ alignas(16) char Cn[8192];    // [64t][64n]
  __shared__ alignas(16) char Bt2[8192];   // [64n][64s]
  __shared__ alignas(16) char Mm[8192];    // [64t][64s]
  __shared__ float aa[QC + 1];
  __shared__ float dts[QC];
  __shared__ float wsum[4];
  int blk2 = blockIdx.x;                   // 512 blocks
  int half = blk2 & 1, blk = blk2 >> 1;
  int c8 = blk & 7, bh = blk >> 3;
  int h = bh & 7, b = bh >> 3;
  int pbase = half * 128;
  int tid = threadIdx.x, wave = tid >> 6, lane = tid & 63;
  int lrow = lane & 15, lk = lane >> 4;
  int rowbase = b * SEQLEN + c8 * QC;
  prefix_aa(ldA[(rowbase + tid) * NH + h], aa, wsum, tid);
  dts[tid] = dtg[(rowbase + tid) * NH + h];
  __syncthreads();
  float Dh = Dp[h];

  f32x4 hcc[2][4];
  const float* hp = Hg + (size_t)blk * 16384;
#pragma unroll
  for (int i = 0; i < 2; ++i)
#pragma unroll
    for (int j = 0; j < 4; ++j)
#pragma unroll
      for (int r = 0; r < 4; ++r)
        hcc[i][j][r] = hp[(size_t)(pbase + wave * 32 + i * 16 + lk * 4 + r) * 64 + j * 16 + lrow];

  for (int sc = 0; sc < 4; ++sc) {
    int s0 = sc * SC;
    // h -> Hb bf16 (wave-local rows)
#pragma unroll
    for (int i = 0; i < 2; ++i)
#pragma unroll
      for (int j = 0; j < 4; ++j)
#pragma unroll
        for (int r = 0; r < 4; ++r) {
          int pl = wave * 32 + i * 16 + lk * 4 + r;
          int n = j * 16 + lrow;
          *(short*)(Hb + pl * 128 + ((n * 2) ^ ((pl & 7) << 4))) = f2bf(hcc[i][j][r]);
        }
#pragma unroll
    for (int it = 0; it < 4; ++it) {     // Xb: 128 rows
      int p = it * 4096 + tid * 16;
      int row = p >> 7, c = p & 127;
      int scz = c ^ ((row & 7) << 4);
      gload_lds16((const char*)(xT + (size_t)(h * HD + pbase + row) * ROWS + rowbase + s0) + scz, Xb + p);
    }
#pragma unroll
    for (int it = 0; it < 2; ++it) {
      int p = it * 4096 + tid * 16;
      int row = p >> 7, c = p & 127;
      int scz = c ^ ((row & 7) << 4);
      gload_lds16((const char*)(bc + (size_t)(rowbase + s0 + row) * 128) + scz, Bn + p);
      gload_lds16((const char*)(bc + (size_t)(rowbase + s0 + row) * 128 + NS) + scz, Cn + p);
      gload_lds16((const char*)(bTg + (size_t)row * ROWS + rowbase + s0) + scz, Bt2 + p);
    }
    asm volatile("s_waitcnt vmcnt(0)" ::: "memory");
    __syncthreads();  // S1

    // G = C * B^T (wave owns t-rows [16w,16w+16))
    f32x4 gcc[4];
#pragma unroll
    for (int j = 0; j < 4; ++j) gcc[j] = (f32x4)0.f;
#pragma unroll
    for (int kk = 0; kk < 2; ++kk) {
      short8 avc = fragr(Cn, wave * 16 + lrow, kk * 64 + lk * 16);
#pragma unroll
      for (int j = 0; j < 4; ++j) {
        short8 bvb = fragr(Bn, j * 16 + lrow, kk * 64 + lk * 16);
        gcc[j] = __builtin_amdgcn_mfma_f32_16x16x32_bf16(avc, bvb, gcc[j], 0, 0, 0);
      }
    }
#pragma unroll
    for (int j = 0; j < 4; ++j)
#pragma unroll
      for (int r = 0; r < 4; ++r) {
        int t = wave * 16 + lk * 4 + r;
        int s = j * 16 + lrow;
        float val = (s <= t) ? gcc[j][r] * __expf(aa[s0 + t + 1] - aa[s0 + s + 1]) * dts[s0 + s]
                             : 0.f;
        *(short*)(Mm + t * 128 + ((s * 2) ^ ((t & 7) << 4))) = f2bf(val);
      }
#pragma unroll
    for (int pass = 0; pass < 2; ++pass) {
      int t = wave * 16 + (lane >> 3) + pass * 8;
      int g = lane & 7;
      int off = t * 128 + g * 16;
      float fac = __expf(aa[s0 + t + 1] - aa[s0]);
      short8 v = *(short8*)(Cn + off);
      short8 o;
#pragma unroll
      for (int j = 0; j < 8; ++j) o[j] = f2bf(bf2f(v[j]) * fac);
      *(short8*)(Cn + off) = o;
    }
    __syncthreads();  // S2

    // Y = M@X + Ce@h  (ycc[t 4][p 2], wave p-slab = 32 rows)
    f32x4 ycc[4][2];
#pragma unroll
    for (int i = 0; i < 4; ++i)
#pragma unroll
      for (int j = 0; j < 2; ++j) ycc[i][j] = (f32x4)0.f;
#pragma unroll
    for (int kk = 0; kk < 2; ++kk) {
      short8 av[4], bv[2];
#pragma unroll
      for (int i = 0; i < 4; ++i)
        av[i] = fragr(Mm, i * 16 + lrow, kk * 64 + lk * 16);
#pragma unroll
      for (int j = 0; j < 2; ++j)
        bv[j] = fragr(Xb, wave * 32 + j * 16 + lrow, kk * 64 + lk * 16);
#pragma unroll
      for (int i = 0; i < 4; ++i)
#pragma unroll
        for (int j = 0; j < 2; ++j)
          ycc[i][j] = __builtin_amdgcn_mfma_f32_16x16x32_bf16(av[i], bv[j], ycc[i][j], 0, 0, 0);
    }
#pragma unroll
    for (int kk = 0; kk < 2; ++kk) {
      short8 av[4], bv[2];
#pragma unroll
      for (int i = 0; i < 4; ++i)
        av[i] = fragr(Cn, i * 16 + lrow, kk * 64 + lk * 16);
#pragma unroll
      for (int j = 0; j < 2; ++j)
        bv[j] = fragr(Hb, wave * 32 + j * 16 + lrow, kk * 64 + lk * 16);
#pragma unroll
      for (int i = 0; i < 4; ++i)
#pragma unroll
        for (int j = 0; j < 2; ++j)
          ycc[i][j] = __builtin_amdgcn_mfma_f32_16x16x32_bf16(av[i], bv[j], ycc[i][j], 0, 0, 0);
    }
#pragma unroll
    for (int i = 0; i < 4; ++i)
#pragma unroll
      for (int j = 0; j < 2; ++j)
#pragma unroll
        for (int r = 0; r < 4; ++r) {
          int t = i * 16 + lk * 4 + r;
          int pl = wave * 32 + j * 16 + lrow;
          float xv = bf2f(*(const short*)(Xb + pl * 128 + ((t * 2) ^ ((pl & 7) << 4))));
          yfull[(size_t)(rowbase + s0 + t) * DINNER + h * HD + pbase + pl] = f2bf(ycc[i][j][r] + Dh * xv);
        }
    {  // scale Xb in place (wave-local rows, granule half by lane>>5)
      int row = wave * 32 + (lane & 31);
      int gb = (lane >> 5) * 4;
      float aend = aa[s0 + SC];
#pragma unroll
      for (int gi = 0; gi < 4; ++gi) {
        int g = gb + gi;
        int off = row * 128 + g * 16;
        int sb = s0 + (((g * 16) ^ ((row & 7) << 4)) >> 1);
        short8 v = *(short8*)(Xb + off);
        short8 o;
#pragma unroll
        for (int j = 0; j < 8; ++j)
          o[j] = f2bf(bf2f(v[j]) * __expf(aend - aa[sb + j + 1]) * dts[sb + j]);
        *(short8*)(Xb + off) = o;
      }
    }
    {  // h = P_sub*h + Xw^T @ B
      float Ps = __expf(aa[s0 + SC] - aa[s0]);
#pragma unroll
      for (int i = 0; i < 2; ++i)
#pragma unroll
        for (int j = 0; j < 4; ++j) hcc[i][j] *= Ps;
#pragma unroll
      for (int kk = 0; kk < 2; ++kk) {
        short8 av[2], bv[4];
#pragma unroll
        for (int i = 0; i < 2; ++i)
          av[i] = fragr(Xb, wave * 32 + i * 16 + lrow, kk * 64 + lk * 16);
#pragma unroll
        for (int j = 0; j < 4; ++j)
          bv[j] = fragr(Bt2, j * 16 + lrow, kk * 64 + lk * 16);
#pragma unroll
        for (int i = 0; i < 2; ++i)
#pragma unroll
          for (int j = 0; j < 4; ++j)
            hcc[i][j] = __builtin_amdgcn_mfma_f32_16x16x32_bf16(av[i], bv[j], hcc[i][j], 0, 0, 0);
      }
    }
    __syncthreads();  // S3
  }
}

// ---------------- gate (silu(z)) + RMSNorm -> bf16 ----------------
__global__ __launch_bounds__(256)
void gate_norm_kernel(const short* __restrict__ yfull, const short* __restrict__ zb,
                      const float* __restrict__ norm_w, short* __restrict__ yn) {
  int row = blockIdx.x, tid = threadIdx.x;
  size_t yb = (size_t)row * DINNER;
  float v[8];
  float ss = 0.f;
#pragma unroll
  for (int g = 0; g < 2; ++g) {
    int cidx = g * 1024 + tid * 4;
    short4v y4 = *(const short4v*)(yfull + yb + cidx);
    short4v z4 = *(const short4v*)(zb + yb + cidx);
#pragma unroll
    for (int j = 0; j < 4; ++j) {
      float z = bf2f(z4[j]);
      float val = bf2f(y4[j]) * z * sigmoidf_fast(z);
      v[g * 4 + j] = val;
      ss = fmaf(val, val, ss);
    }
  }
#pragma unroll
  for (int o = 32; o; o >>= 1) ss += __shfl_down(ss, o);
  __shared__ float red[4];
  if ((tid & 63) == 0) red[tid >> 6] = ss;
  __syncthreads();
  float tot = red[0] + red[1] + red[2] + red[3];
  float scale = rsqrtf(tot * (1.f / (float)DINNER) + 1e-5f);
#pragma unroll
  for (int g = 0; g < 2; ++g) {
    int cidx = g * 1024 + tid * 4;
    short4v o4;
#pragma unroll
    for (int j = 0; j < 4; ++j) o4[j] = f2bf(v[g * 4 + j] * scale * norm_w[cidx + j]);
    *(short4v*)(yn + yb + cidx) = o4;
  }
}

// ---------------- launcher ----------------
extern "C" void kernel_launch(void* const* d_in, const int* in_sizes, int n_in,
                              void* d_out, int out_size, void* d_ws, size_t ws_size,
                              hipStream_t stream) {
  (void)in_sizes; (void)n_in; (void)out_size; (void)ws_size;
  const float* x     = (const float*)d_in[0];
  const float* W_in  = (const float*)d_in[1];
  const float* convw = (const float*)d_in[2];
  const float* convb = (const float*)d_in[3];
  const float* dtb   = (const float*)d_in[4];
  const float* Alog  = (const float*)d_in[5];
  const float* Dp    = (const float*)d_in[6];
  const float* inis  = (const float*)d_in[7];
  const float* nw    = (const float*)d_in[8];
  const float* W_out = (const float*)d_in[9];
  const float* W_nl  = (const float*)d_in[10];
  const float* b_nl  = (const float*)d_in[11];
  float* out = (float*)d_out;
  char* ws = (char*)d_ws;

  short* woutT  = (short*)(ws + O_WOUT);
  short* wnlT   = (short*)(ws + O_WNL);
  float* dtg    = (float*)(ws + O_DT);
  float* ldA    = (float*)(ws + O_LDA);
  float* Pg     = (float*)(ws + O_PG);
  short* bTg    = (short*)(ws + O_BT);
  short* zb     = (short*)(ws + O_ZB);
  short* xbcpre = (short*)(ws + O_XBCPRE);
  float* Sg     = (float*)(ws + O_SG);
  float* Hg     = (float*)(ws + O_HG);
  short* tb     = (short*)(ws + O_TB);
  short* bc     = (short*)(ws + O_XBC);
  short* yn     = (short*)(ws + O_YN);
  short* xT     = (short*)(ws + O_XTR);
  short* xbf    = (short*)(ws + O_XBF);
  short* winT   = (short*)(ws + O_WIN);
  float* wtailT = (float*)(ws + O_WTAIL);
  short* yfull  = (short*)d_out;

  prep_weights_kernel<<<1856, 256, 0, stream>>>(W_in, W_out, W_nl, winT, woutT, wnlT, wtailT);
  cast_dt_kernel<<<ROWS, 256, 0, stream>>>(x, wtailT, dtb, Alog, xbf, dtg, ldA);

  // GEMM1: M=8192 (32 tiles of 256), N=4224 (33 tiles of 128), K=1024 -> 1056 blocks
  gemm1_256<<<32 * 33, 512, 0, stream>>>(xbf, winT, HM, 33, zb, xbcpre);
  conv_silu_kernel<<<17 * 32 * 4, 256, 0, stream>>>(xbcpre, convw, convb, bc, xT, bTg);

  scan_passA_mfma<<<32 * NC * 2, 256, 0, stream>>>(xT, bTg, dtg, ldA, Sg, Pg);
  scan_passB<<<32 * 16, 256, 0, stream>>>(Sg, Pg, inis, Hg);
  scan_passC_mfma<<<32 * NC * 2, 256, 0, stream>>>(xT, bTg, bc, dtg, ldA, Hg, Dp, yfull);

  gate_norm_kernel<<<ROWS, 256, 0, stream>>>(yfull, zb, nw, yn);
  // GEMM2: M=8192, N=1024 (8x128), K=2048 -> 256 blocks
  gemm8p<1><<<32 * 8, 512, 0, stream>>>(yn, woutT, DINNER, 8, HM, nullptr, tb, nullptr, nullptr);
  // GEMM3: M=8192, N=1024, K=1024 -> 256 blocks
  gemm8p<2><<<32 * 8, 512, 0, stream>>>(tb, wnlT, HM, 8, HM, out, nullptr, b_nl, x);
}

// Round 16
// 287.052 us; speedup vs baseline: 1.0599x; 1.0124x over previous
//
#include <hip/hip_runtime.h>
#include <stdint.h>
#include <stddef.h>

// ---------------- problem dims ----------------
#define BATCH   4
#define SEQLEN  2048
#define HM      1024
#define DINNER  2048
#define NH      8
#define HD      256
#define NS      64
#define CONVD   2176
#define DCONV   16
#define DPROJ   4232
#define ROWS    (BATCH*SEQLEN)  // 8192
#define QC      256             // big-chunk length
#define NC      (SEQLEN/QC)     // 8 big-chunks
#define SC      64              // sub-chunk length (passC)
#define TT      16              // conv timesteps per thread

typedef __attribute__((ext_vector_type(8))) short short8;
typedef __attribute__((ext_vector_type(4))) short short4v;
typedef __attribute__((ext_vector_type(4))) float f32x4;

// ---------------- workspace layout (bytes) ----------------
static constexpr size_t O_WOUT   = 0;                    //  4,194,304
static constexpr size_t O_WNL    = 4194304;              //  2,097,152
static constexpr size_t O_DT     = 6291456;              //    262,144
static constexpr size_t O_LDA    = 6553600;              //    262,144
static constexpr size_t O_PG     = 6815744;              //      4,096
static constexpr size_t O_BT     = 6819840;              //  1,048,576
static constexpr size_t O_ZB     = 7868416;              // 33,554,432  bf16 z[8192][2048]
static constexpr size_t O_XBCPRE = 41422848;             // 35,651,584  bf16 [8192][2176]
static constexpr size_t O_SG     = O_XBCPRE;             //  8,388,608  bf16 [65536][64]
static constexpr size_t O_HG     = O_XBCPRE + 8388608;   //  8,388,608  bf16 [256][16384]
static constexpr size_t O_TB     = O_XBCPRE;             // 16,777,216  bf16 [8192][1024] (after scan)
static constexpr size_t O_XBC    = 77074432;             // bc[8192][128] bf16 (2MB); later yn[8192][2048]
static constexpr size_t O_YN     = O_XBC;
static constexpr size_t O_XTR    = 112726016;            // 33,554,432  bf16 xT[2048][8192]
static constexpr size_t O_XBF    = O_XTR;                // 16,777,216  bf16 [8192][1024]
static constexpr size_t O_WIN    = O_XTR + 16777216;     //  8,912,896  bf16 [4352][1024]
static constexpr size_t O_WTAIL  = 146280448;            //     32,768  f32 wtailT[8][1024]
// END = 146,313,216

// ---------------- helpers ----------------
__device__ __forceinline__ short f2bf(float f) {
  union { float f; uint32_t u; } v; v.f = f;
  uint32_t r = v.u + 0x7fffu + ((v.u >> 16) & 1u);
  return (short)(r >> 16);
}

__device__ __forceinline__ float bf2f(short s) {
  union { float f; uint32_t u; } v;
  v.u = ((uint32_t)(uint16_t)s) << 16;
  return v.f;
}

__device__ __forceinline__ void gload_lds16(const void* g, void* l) {
  __builtin_amdgcn_global_load_lds(
      (const __attribute__((address_space(1))) uint32_t*)g,
      (__attribute__((address_space(3))) uint32_t*)l, 16, 0, 0);
}

__device__ __forceinline__ float sigmoidf_fast(float x) {
  return 1.f / (1.f + __expf(-x));
}

// fragment read from a [rows][64-elem] bf16 LDS tile (128B rows, XOR-swizzled)
__device__ __forceinline__ short8 fragr(const char* base, int row, int kbyte) {
  return *(const short8*)(base + row * 128 + (kbyte ^ ((row & 7) << 4)));
}

// ---------------- wtail extraction (runs first; tiny) ----------------------
__global__ __launch_bounds__(256)
void wtail_kernel(const float* __restrict__ W_in, float* __restrict__ wtailT) {
  int i = blockIdx.x * 256 + threadIdx.x;  // 8192 elems
  int h = i >> 10, k = i & 1023;
  wtailT[i] = W_in[(size_t)k * DPROJ + (DPROJ - NH) + h];
}

// ---------------- merged weight transposes + cast/dt (independent work) ----
__device__ __forceinline__ void transpose_tile(const float* __restrict__ W,
                                               short* __restrict__ Wt,
                                               int idx, int srcN, int validN,
                                               int Kdim, int nTilesN, int tid) {
  __shared__ short lds[64][72];
  int k0 = (idx / nTilesN) * 64;
  int n0 = (idx % nTilesN) * 64;
  int rr = tid >> 4;
  int cc = (tid & 15) * 4;
#pragma unroll
  for (int pass = 0; pass < 4; ++pass) {
    int k = pass * 16 + rr;
    int gn = n0 + cc;
    f32x4 v = (f32x4)0.f;
    if (gn < validN) v = *(const f32x4*)(W + (size_t)(k0 + k) * srcN + gn);
    uint32_t p0 = (uint32_t)(uint16_t)f2bf(v[0]) | ((uint32_t)(uint16_t)f2bf(v[1]) << 16);
    uint32_t p1 = (uint32_t)(uint16_t)f2bf(v[2]) | ((uint32_t)(uint16_t)f2bf(v[3]) << 16);
    *(uint32_t*)&lds[k][cc] = p0;
    *(uint32_t*)&lds[k][cc + 2] = p1;
  }
  __syncthreads();
  int n = tid >> 2;
  int ks = (tid & 3) * 16;
  short8 a, b;
#pragma unroll
  for (int j = 0; j < 8; ++j) a[j] = lds[ks + j][n];
#pragma unroll
  for (int j = 0; j < 8; ++j) b[j] = lds[ks + 8 + j][n];
  short* dst = Wt + (size_t)(n0 + n) * Kdim + k0 + ks;
  *(short8*)dst = a;
  *(short8*)(dst + 8) = b;
}

__global__ __launch_bounds__(256)
void prep_cast_kernel(const float* __restrict__ W_in, const float* __restrict__ W_out,
                      const float* __restrict__ W_nl,
                      short* __restrict__ winT, short* __restrict__ woutT,
                      short* __restrict__ wnlT,
                      const float* __restrict__ x, const float* __restrict__ wtailT,
                      const float* __restrict__ dt_bias, const float* __restrict__ A_log,
                      short* __restrict__ xbf, float* __restrict__ dtg,
                      float* __restrict__ ldA) {
  int bid = blockIdx.x, tid = threadIdx.x;
  if (bid < 1056) {           // W_in^T: 16 k-tiles x 66 n-tiles (n<4224 only)
    transpose_tile(W_in, winT, bid, DPROJ, DPROJ, HM, 66, tid);
  } else if (bid < 1568) {    // W_out^T: 32 k-tiles x 16 n-tiles
    transpose_tile(W_out, woutT, bid - 1056, HM, HM, DINNER, 16, tid);
  } else if (bid < 1824) {    // W_nl^T: 16 x 16
    transpose_tile(W_nl, wnlT, bid - 1568, HM, HM, HM, 16, tid);
  } else {                    // fused cast x -> bf16 + exact-f32 dt/ldA
    int row = bid - 1824;
    f32x4 xv = ((const f32x4*)(x + (size_t)row * HM))[tid];
    short4v o = { f2bf(xv[0]), f2bf(xv[1]), f2bf(xv[2]), f2bf(xv[3]) };
    ((short4v*)(xbf + (size_t)row * HM))[tid] = o;
    float p[NH];
#pragma unroll
    for (int h = 0; h < NH; ++h) {
      f32x4 w = ((const f32x4*)(wtailT + h * HM))[tid];
      p[h] = xv[0] * w[0] + xv[1] * w[1] + xv[2] * w[2] + xv[3] * w[3];
    }
#pragma unroll
    for (int h = 0; h < NH; ++h)
#pragma unroll
      for (int of = 32; of; of >>= 1) p[h] += __shfl_down(p[h], of);
    __shared__ float red[4][NH];
    int lane = tid & 63, w4 = tid >> 6;
    if (lane == 0)
#pragma unroll
      for (int h = 0; h < NH; ++h) red[w4][h] = p[h];
    __syncthreads();
    if (tid < NH) {
      float s = red[0][tid] + red[1][tid] + red[2][tid] + red[3][tid] + dt_bias[tid];
      float dtv = (s > 20.f) ? s : log1pf(expf(s));
      float A = -expf(A_log[tid]);
      dtg[row * NH + tid] = dtv;
      ldA[row * NH + tid] = dtv * A;
    }
  }
}

// ---------------- parallel inclusive prefix of ldA into aa[257] ------------
__device__ __forceinline__ void prefix_aa(float av, float* aa, float* wsum,
                                          int tid) {
  float v = av;
  int lane = tid & 63;
#pragma unroll
  for (int o = 1; o < 64; o <<= 1) {
    float u = __shfl_up(v, o);
    if (lane >= o) v += u;
  }
  if (lane == 63) wsum[tid >> 6] = v;
  __syncthreads();
  float off = 0.f;
  int w4 = tid >> 6;
#pragma unroll
  for (int w = 0; w < 4; ++w)
    if (w < w4) off += wsum[w];
  aa[tid + 1] = v + off;
  if (tid == 0) aa[0] = 0.f;
  __syncthreads();
}

// ---------------- GEMM1: 256x128 tile, BK=64, 1-phase, 3 blocks/CU ---------
__global__ __launch_bounds__(512)
void gemm1_256(const short* __restrict__ A, const short* __restrict__ B,
               int K, int nTilesN,
               short* __restrict__ Cb, short* __restrict__ Cb2) {
  __shared__ alignas(16) char lds[49152];
  char* As = lds;           // [256][128B]
  char* Bs = lds + 32768;   // [128][128B]
  const int tid = threadIdx.x;
  int bid = blockIdx.x;
  {
    int nwg = gridDim.x;
    if ((nwg & 7) == 0) bid = (bid & 7) * (nwg >> 3) + (bid >> 3);
  }
  const int m0 = (bid / nTilesN) * 256;
  const int n0 = (bid % nTilesN) * 128;
  const int lane = tid & 63;
  const int wid = tid >> 6;        // 8 waves: 4M x 2N
  const int wm = wid >> 1;
  const int wn = wid & 1;
  const int lrow = lane & 15, lk = lane >> 4;

  f32x4 acc[4][4];
#pragma unroll
  for (int i = 0; i < 4; ++i)
#pragma unroll
    for (int j = 0; j < 4; ++j) acc[i][j] = (f32x4)0.f;

  for (int k0 = 0; k0 < K; k0 += 64) {
#pragma unroll
    for (int r = 0; r < 4; ++r) {  // A: 256 rows x 128B
      int p = r * 8192 + tid * 16;
      int row = p >> 7, c = p & 127;
      int sc = c ^ ((row & 7) << 4);
      gload_lds16((const char*)A + ((size_t)(m0 + row) * K + k0) * 2 + sc, As + p);
    }
#pragma unroll
    for (int r = 0; r < 2; ++r) {  // B: 128 rows x 128B
      int p = r * 8192 + tid * 16;
      int row = p >> 7, c = p & 127;
      int sc = c ^ ((row & 7) << 4);
      gload_lds16((const char*)B + ((size_t)(n0 + row) * K + k0) * 2 + sc, Bs + p);
    }
    asm volatile("s_waitcnt vmcnt(0)" ::: "memory");
    __syncthreads();
#pragma unroll
    for (int ks = 0; ks < 2; ++ks) {
      short8 av[4], bv[4];
#pragma unroll
      for (int i = 0; i < 4; ++i) {
        av[i] = fragr(As, wm * 64 + i * 16 + lrow, ks * 64 + lk * 16);
        bv[i] = fragr(Bs, wn * 64 + i * 16 + lrow, ks * 64 + lk * 16);
      }
#pragma unroll
      for (int i = 0; i < 4; ++i)
#pragma unroll
        for (int j = 0; j < 4; ++j)
          acc[i][j] = __builtin_amdgcn_mfma_f32_16x16x32_bf16(av[i], bv[j], acc[i][j], 0, 0, 0);
    }
    __syncthreads();
  }

  const int row0 = m0 + wm * 64, col0 = n0 + wn * 64;
#pragma unroll
  for (int i = 0; i < 4; ++i)
#pragma unroll
    for (int j = 0; j < 4; ++j)
#pragma unroll
      for (int r = 0; r < 4; ++r) {
        int row = row0 + i * 16 + lk * 4 + r;
        int col = col0 + j * 16 + lrow;
        float v = acc[i][j][r];
        if (col < DINNER) Cb[(size_t)row * DINNER + col] = f2bf(v);
        else if (col < DINNER + CONVD) Cb2[(size_t)row * CONVD + (col - DINNER)] = f2bf(v);
      }
}

// ---------------- 8-wave 256x128 pipelined bf16 GEMM (2-phase/K-tile) ------
template <int EPI>
__global__ __launch_bounds__(512)
void gemm8p(const short* __restrict__ A, const short* __restrict__ B,
            int K, int nTilesN, int N_out,
            float* __restrict__ Cf, short* __restrict__ Cb,
            const float* __restrict__ bias, const float* __restrict__ resid) {
  __shared__ alignas(16) char lds[147456];  // 3 slots x 48KB
  const int tid = threadIdx.x;
  int bid = blockIdx.x;
  {
    int nwg = gridDim.x;
    if ((nwg & 7) == 0) bid = (bid & 7) * (nwg >> 3) + (bid >> 3);
  }
  const int m0 = (bid / nTilesN) * 256;
  const int n0 = (bid % nTilesN) * 128;
  const int lane = tid & 63;
  const int wid = tid >> 6;
  const int wm = wid >> 1;
  const int wn = wid & 1;
  const int lrow = lane & 15, lk = lane >> 4;
  const int nK = K >> 6;

#define LDSA(s) (lds + (s) * 49152)
#define LDSB(s) (lds + (s) * 49152 + 32768)

#define STAGE_A(s, kt, it) do {                                              \
    int p_ = (it) * 8192 + tid * 16;                                         \
    int row_ = p_ >> 7, c_ = p_ & 127;                                       \
    int sc_ = c_ ^ ((row_ & 7) << 4);                                        \
    gload_lds16((const char*)A + ((size_t)(m0 + row_) * K + (kt) * 64) * 2 + sc_, \
                LDSA(s) + p_);                                               \
  } while (0)
#define STAGE_B(s, kt, it) do {                                              \
    int p_ = (it) * 8192 + tid * 16;                                         \
    int row_ = p_ >> 7, c_ = p_ & 127;                                       \
    int sc_ = c_ ^ ((row_ & 7) << 4);                                        \
    gload_lds16((const char*)B + ((size_t)(n0 + row_) * K + (kt) * 64) * 2 + sc_, \
                LDSB(s) + p_);                                               \
  } while (0)

  f32x4 acc[4][4];
#pragma unroll
  for (int i = 0; i < 4; ++i)
#pragma unroll
    for (int j = 0; j < 4; ++j) acc[i][j] = (f32x4)0.f;

#pragma unroll
  for (int it = 0; it < 4; ++it) STAGE_A(0, 0, it);
#pragma unroll
  for (int it = 0; it < 2; ++it) STAGE_B(0, 0, it);
#pragma unroll
  for (int it = 0; it < 4; ++it) STAGE_A(1, 1, it);
#pragma unroll
  for (int it = 0; it < 2; ++it) STAGE_B(1, 1, it);
  asm volatile("s_waitcnt vmcnt(6)" ::: "memory");
  __builtin_amdgcn_s_barrier();

  for (int kt = 0; kt < nK; ++kt) {
    const int rs = kt % 3;
    const int ss = (kt + 2) % 3;
    const bool st = (kt + 2) < nK;
    const char* Ab = LDSA(rs);
    const char* Bb = LDSB(rs);
    short8 aF[4][2], bF[4][2];

#pragma unroll
    for (int ii = 0; ii < 4; ++ii)
#pragma unroll
      for (int ks = 0; ks < 2; ++ks)
        aF[ii][ks] = fragr(Ab, wm * 64 + ii * 16 + lrow, ks * 64 + lk * 16);
#pragma unroll
    for (int jj = 0; jj < 2; ++jj)
#pragma unroll
      for (int ks = 0; ks < 2; ++ks)
        bF[jj][ks] = fragr(Bb, wn * 64 + jj * 16 + lrow, ks * 64 + lk * 16);
    if (st) { STAGE_A(ss, kt + 2, 0); STAGE_A(ss, kt + 2, 1); STAGE_A(ss, kt + 2, 2); STAGE_A(ss, kt + 2, 3); }
    __builtin_amdgcn_s_barrier();
    asm volatile("s_waitcnt lgkmcnt(0)" ::: "memory");
    __builtin_amdgcn_s_setprio(1);
#pragma unroll
    for (int ii = 0; ii < 4; ++ii)
#pragma unroll
      for (int jj = 0; jj < 2; ++jj)
#pragma unroll
        for (int ks = 0; ks < 2; ++ks)
          acc[ii][jj] = __builtin_amdgcn_mfma_f32_16x16x32_bf16(aF[ii][ks], bF[jj][ks], acc[ii][jj], 0, 0, 0);
    __builtin_amdgcn_s_setprio(0);
    __builtin_amdgcn_s_barrier();

#pragma unroll
    for (int jj = 2; jj < 4; ++jj)
#pragma unroll
      for (int ks = 0; ks < 2; ++ks)
        bF[jj][ks] = fragr(Bb, wn * 64 + jj * 16 + lrow, ks * 64 + lk * 16);
    if (st) { STAGE_B(ss, kt + 2, 0); STAGE_B(ss, kt + 2, 1); }
    __builtin_amdgcn_s_barrier();
    asm volatile("s_waitcnt lgkmcnt(0)" ::: "memory");
    __builtin_amdgcn_s_setprio(1);
#pragma unroll
    for (int ii = 0; ii < 4; ++ii)
#pragma unroll
      for (int jj = 2; jj < 4; ++jj)
#pragma unroll
        for (int ks = 0; ks < 2; ++ks)
          acc[ii][jj] = __builtin_amdgcn_mfma_f32_16x16x32_bf16(aF[ii][ks], bF[jj][ks], acc[ii][jj], 0, 0, 0);
    __builtin_amdgcn_s_setprio(0);
    if (kt >= nK - 2) {
      asm volatile("s_waitcnt vmcnt(0)" ::: "memory");
    } else {
      asm volatile("s_waitcnt vmcnt(6)" ::: "memory");
    }
    __builtin_amdgcn_s_barrier();
  }

  const int row0 = m0 + wm * 64, col0 = n0 + wn * 64;
#pragma unroll
  for (int i = 0; i < 4; ++i)
#pragma unroll
    for (int j = 0; j < 4; ++j)
#pragma unroll
      for (int r = 0; r < 4; ++r) {
        int row = row0 + i * 16 + lk * 4 + r;
        int col = col0 + j * 16 + lrow;
        float v = acc[i][j][r];
        if (EPI == 1) {
          float t = v * rsqrtf(1.f + v * v);
          Cb[(size_t)row * N_out + col] = f2bf(t);
        } else if (EPI == 2) {
          Cf[(size_t)row * N_out + col] = v + bias[col] + resid[(size_t)row * N_out + col];
        }
      }
#undef LDSA
#undef LDSB
#undef STAGE_A
#undef STAGE_B
}

// ---------------- depthwise causal conv16 + SiLU, register-blocked ----------
__global__ __launch_bounds__(256) void conv_silu_kernel(const short* __restrict__ xbcpre,
                                                        const float* __restrict__ cw,
                                                        const float* __restrict__ cbias,
                                                        short* __restrict__ bc,
                                                        short* __restrict__ xT,
                                                        short* __restrict__ bTg) {
  __shared__ short tld[64][130];   // [t][128 ch + 2 pad]
  int blk = blockIdx.x;            // 17*32*4
  int cg = blk % 17;
  int tg = (blk / 17) % 32;
  int b  = blk / (17 * 32);
  int lane = threadIdx.x & 63;
  int warp = threadIdx.x >> 6;
  int c0 = cg * 128 + lane * 2;
  int tbase = (tg * 4 + warp) * TT;

  const short* inp = xbcpre + (size_t)(b * SEQLEN) * CONVD + c0;
  uint32_t in[TT + DCONV - 1];
#pragma unroll
  for (int j = 0; j < TT + DCONV - 1; ++j) {
    int t = tbase + j - (DCONV - 1);
    in[j] = (t >= 0) ? *(const uint32_t*)(inp + (size_t)t * CONVD) : 0u;
  }
  float w0[DCONV], w1[DCONV];
  const float* wp = cw + (size_t)c0 * DCONV;
#pragma unroll
  for (int k = 0; k < DCONV; ++k) { w0[k] = wp[k]; w1[k] = wp[DCONV + k]; }
  float bb0 = cbias[c0], bb1 = cbias[c0 + 1];

  const bool isBC = (cg == 16);
  short* bcp = bc + (size_t)(b * SEQLEN) * 128 + (c0 - DINNER);
#pragma unroll
  for (int tt = 0; tt < TT; ++tt) {
    float a0 = bb0, a1 = bb1;
#pragma unroll
    for (int k = 0; k < DCONV; ++k) {
      uint32_t v = in[tt + k];
      a0 = fmaf(bf2f((short)(v & 0xffffu)), w0[k], a0);
      a1 = fmaf(bf2f((short)(v >> 16)), w1[k], a1);
    }
    a0 = a0 * sigmoidf_fast(a0);
    a1 = a1 * sigmoidf_fast(a1);
    uint32_t o = (uint32_t)(uint16_t)f2bf(a0) | ((uint32_t)(uint16_t)f2bf(a1) << 16);
    if (isBC) *(uint32_t*)(bcp + (size_t)(tbase + tt) * 128) = o;
    *(uint32_t*)&tld[warp * TT + tt][lane * 2] = o;
  }
  __syncthreads();
  int ch = threadIdx.x & 127;
  int seg = threadIdx.x >> 7;
  int gc = cg * 128 + ch;
  short* dst = nullptr;
  if (gc < DINNER) dst = xT + (size_t)gc * ROWS;
  else if (gc < DINNER + NS) dst = bTg + (size_t)(gc - DINNER) * ROWS;
  if (dst) {
    int tcol = b * SEQLEN + tg * 64 + seg * 32;
    short8 v[4];
#pragma unroll
    for (int q = 0; q < 4; ++q)
#pragma unroll
      for (int j = 0; j < 8; ++j) v[q][j] = tld[seg * 32 + q * 8 + j][ch];
    short8* dp = (short8*)(dst + tcol);
    dp[0] = v[0]; dp[1] = v[1]; dp[2] = v[2]; dp[3] = v[3];
  }
}

// ---------------- scan pass A (MFMA, p-split x2): chunk state contribution --
__global__ __launch_bounds__(256)
void scan_passA_mfma(const short* __restrict__ xT, const short* __restrict__ bTg,
                     const float* __restrict__ dtg, const float* __restrict__ ldA,
                     short* __restrict__ Sg, float* __restrict__ Pg) {
  __shared__ alignas(16) char Ax[16384];   // [128p][64s]
  __shared__ alignas(16) char Bt[8192];    // [64n][64s]
  __shared__ float aa[QC + 1];
  __shared__ float wdt[QC];
  __shared__ float wsum[4];
  int blk2 = blockIdx.x;                   // 512 blocks: (blk, half)
  int half = blk2 & 1, blk = blk2 >> 1;
  int c8 = blk & 7, bh = blk >> 3;
  int h = bh & 7, b = bh >> 3;
  int pbase = half * 128;
  int tid = threadIdx.x, wave = tid >> 6, lane = tid & 63;
  int lrow = lane & 15, lk = lane >> 4;
  int rowbase = b * SEQLEN + c8 * QC;
  prefix_aa(ldA[(rowbase + tid) * NH + h], aa, wsum, tid);
  float alast = aa[QC];
  if (tid == 0 && half == 0) Pg[blk] = __expf(alast);
  wdt[tid] = __expf(alast - aa[tid + 1]) * dtg[(rowbase + tid) * NH + h];

  f32x4 acc[2][4];
#pragma unroll
  for (int i = 0; i < 2; ++i)
#pragma unroll
    for (int j = 0; j < 4; ++j) acc[i][j] = (f32x4)0.f;

  for (int ks = 0; ks < 4; ++ks) {
    int s0 = ks * 64;
#pragma unroll
    for (int it = 0; it < 4; ++it) {     // 128 rows x 128B
      int p = it * 4096 + tid * 16;
      int row = p >> 7, c = p & 127;
      int sc = c ^ ((row & 7) << 4);
      gload_lds16((const char*)(xT + (size_t)(h * HD + pbase + row) * ROWS + rowbase + s0) + sc, Ax + p);
    }
#pragma unroll
    for (int it = 0; it < 2; ++it) {
      int p = it * 4096 + tid * 16;
      int row = p >> 7, c = p & 127;
      int sc = c ^ ((row & 7) << 4);
      gload_lds16((const char*)(bTg + (size_t)row * ROWS + rowbase + s0) + sc, Bt + p);
    }
    asm volatile("s_waitcnt vmcnt(0)" ::: "memory");
    __syncthreads();
    {  // wave-local scale: wave w scales rows w*32..w*32+31 (granule half by lane>>5)
      int row = wave * 32 + (lane & 31);
      int gb = (lane >> 5) * 4;
#pragma unroll
      for (int gi = 0; gi < 4; ++gi) {
        int g = gb + gi;
        int off = row * 128 + g * 16;
        int sb = s0 + (((g * 16) ^ ((row & 7) << 4)) >> 1);
        short8 v = *(short8*)(Ax + off);
        short8 o;
#pragma unroll
        for (int j = 0; j < 8; ++j) o[j] = f2bf(bf2f(v[j]) * wdt[sb + j]);
        *(short8*)(Ax + off) = o;
      }
    }
    __syncthreads();
#pragma unroll
    for (int kk = 0; kk < 2; ++kk) {
      short8 av[2], bv[4];
#pragma unroll
      for (int i = 0; i < 2; ++i)
        av[i] = fragr(Ax, wave * 32 + i * 16 + lrow, kk * 64 + lk * 16);
#pragma unroll
      for (int j = 0; j < 4; ++j)
        bv[j] = fragr(Bt, j * 16 + lrow, kk * 64 + lk * 16);
#pragma unroll
      for (int i = 0; i < 2; ++i)
#pragma unroll
        for (int j = 0; j < 4; ++j)
          acc[i][j] = __builtin_amdgcn_mfma_f32_16x16x32_bf16(av[i], bv[j], acc[i][j], 0, 0, 0);
    }
    __syncthreads();
  }
#pragma unroll
  for (int i = 0; i < 2; ++i)
#pragma unroll
    for (int j = 0; j < 4; ++j)
#pragma unroll
      for (int r = 0; r < 4; ++r) {
        int p = pbase + wave * 32 + i * 16 + lk * 4 + r;
        int n = j * 16 + lrow;
        Sg[((size_t)blk * 256 + p) * 64 + n] = f2bf(acc[i][j][r]);
      }
}

// ---------------- scan pass B: inter-chunk combine (bf16 S/H) --------------
__global__ __launch_bounds__(256)
void scan_passB(const short* __restrict__ Sg, const float* __restrict__ Pg,
                const float* __restrict__ init, short* __restrict__ Hg) {
  int blk = blockIdx.x;
  int ptile = blk & 15, bh = blk >> 4;
  int h = bh & (NH - 1);
  int tid = threadIdx.x;
  size_t off = (size_t)ptile * 1024 + tid * 4;
  f32x4 hc = *(const f32x4*)(init + (size_t)h * HD * NS + off);
#pragma unroll 1
  for (int c = 0; c < NC; ++c) {
    short4v hb = { f2bf(hc[0]), f2bf(hc[1]), f2bf(hc[2]), f2bf(hc[3]) };
    *(short4v*)(Hg + (size_t)(bh * NC + c) * 16384 + off) = hb;
    float P = Pg[bh * NC + c];
    short4v s4 = *(const short4v*)(Sg + (size_t)(bh * NC + c) * 16384 + off);
    hc[0] = P * hc[0] + bf2f(s4[0]);
    hc[1] = P * hc[1] + bf2f(s4[1]);
    hc[2] = P * hc[2] + bf2f(s4[2]);
    hc[3] = P * hc[3] + bf2f(s4[3]);
  }
}

// ---------------- scan pass C (MFMA, p-split x2): chunked y -----------------
__global__ __launch_bounds__(256)
void scan_passC_mfma(const short* __restrict__ xT, const short* __restrict__ bTg,
                     const short* __restrict__ bc,
                     const float* __restrict__ dtg, const float* __restrict__ ldA,
                     const short* __restrict__ Hg, const float* __restrict__ Dp,
                     short* __restrict__ yfull) {
  __shared__ alignas(16) char Xb[16384];   // [128p][64s]
  __shared__ alignas(16) char Hb[16384];   // [128p][64n]
  __shared__ alignas(16) char Bn[8192];    // [64s][64n]
  __shared__ alignas(16) char Cn[8192];    // [64t][64n]
  __shared__ alignas(16) char Bt2[8192];   // [64n][64s]
  __shared__ alignas(16) char Mm[8192];    // [64t][64s]
  __shared__ float aa[QC + 1];
  __shared__ float dts[QC];
  __shared__ float wsum[4];
  int blk2 = blockIdx.x;                   // 512 blocks
  int half = blk2 & 1, blk = blk2 >> 1;
  int c8 = blk & 7, bh = blk >> 3;
  int h = bh & 7, b = bh >> 3;
  int pbase = half * 128;
  int tid = threadIdx.x, wave = tid >> 6, lane = tid & 63;
  int lrow = lane & 15, lk = lane >> 4;
  int rowbase = b * SEQLEN + c8 * QC;
  prefix_aa(ldA[(rowbase + tid) * NH + h], aa, wsum, tid);
  dts[tid] = dtg[(rowbase + tid) * NH + h];
  __syncthreads();
  float Dh = Dp[h];

  f32x4 hcc[2][4];
  const short* hp = Hg + (size_t)blk * 16384;
#pragma unroll
  for (int i = 0; i < 2; ++i)
#pragma unroll
    for (int j = 0; j < 4; ++j)
#pragma unroll
      for (int r = 0; r < 4; ++r)
        hcc[i][j][r] = bf2f(hp[(size_t)(pbase + wave * 32 + i * 16 + lk * 4 + r) * 64 + j * 16 + lrow]);

  for (int sc = 0; sc < 4; ++sc) {
    int s0 = sc * SC;
    // h -> Hb bf16 (wave-local rows)
#pragma unroll
    for (int i = 0; i < 2; ++i)
#pragma unroll
      for (int j = 0; j < 4; ++j)
#pragma unroll
        for (int r = 0; r < 4; ++r) {
          int pl = wave * 32 + i * 16 + lk * 4 + r;
          int n = j * 16 + lrow;
          *(short*)(Hb + pl * 128 + ((n * 2) ^ ((pl & 7) << 4))) = f2bf(hcc[i][j][r]);
        }
#pragma unroll
    for (int it = 0; it < 4; ++it) {     // Xb: 128 rows
      int p = it * 4096 + tid * 16;
      int row = p >> 7, c = p & 127;
      int scz = c ^ ((row & 7) << 4);
      gload_lds16((const char*)(xT + (size_t)(h * HD + pbase + row) * ROWS + rowbase + s0) + scz, Xb + p);
    }
#pragma unroll
    for (int it = 0; it < 2; ++it) {
      int p = it * 4096 + tid * 16;
      int row = p >> 7, c = p & 127;
      int scz = c ^ ((row & 7) << 4);
      gload_lds16((const char*)(bc + (size_t)(rowbase + s0 + row) * 128) + scz, Bn + p);
      gload_lds16((const char*)(bc + (size_t)(rowbase + s0 + row) * 128 + NS) + scz, Cn + p);
      gload_lds16((const char*)(bTg + (size_t)row * ROWS + rowbase + s0) + scz, Bt2 + p);
    }
    asm volatile("s_waitcnt vmcnt(0)" ::: "memory");
    __syncthreads();  // S1

    // G = C * B^T (wave owns t-rows [16w,16w+16))
    f32x4 gcc[4];
#pragma unroll
    for (int j = 0; j < 4; ++j) gcc[j] = (f32x4)0.f;
#pragma unroll
    for (int kk = 0; kk < 2; ++kk) {
      short8 avc = fragr(Cn, wave * 16 + lrow, kk * 64 + lk * 16);
#pragma unroll
      for (int j = 0; j < 4; ++j) {
        short8 bvb = fragr(Bn, j * 16 + lrow, kk * 64 + lk * 16);
        gcc[j] = __builtin_amdgcn_mfma_f32_16x16x32_bf16(avc, bvb, gcc[j], 0, 0, 0);
      }
    }
#pragma unroll
    for (int j = 0; j < 4; ++j)
#pragma unroll
      for (int r = 0; r < 4; ++r) {
        int t = wave * 16 + lk * 4 + r;
        int s = j * 16 + lrow;
        float val = (s <= t) ? gcc[j][r] * __expf(aa[s0 + t + 1] - aa[s0 + s + 1]) * dts[s0 + s]
                             : 0.f;
        *(short*)(Mm + t * 128 + ((s * 2) ^ ((t & 7) << 4))) = f2bf(val);
      }
#pragma unroll
    for (int pass = 0; pass < 2; ++pass) {
      int t = wave * 16 + (lane >> 3) + pass * 8;
      int g = lane & 7;
      int off = t * 128 + g * 16;
      float fac = __expf(aa[s0 + t + 1] - aa[s0]);
      short8 v = *(short8*)(Cn + off);
      short8 o;
#pragma unroll
      for (int j = 0; j < 8; ++j) o[j] = f2bf(bf2f(v[j]) * fac);
      *(short8*)(Cn + off) = o;
    }
    __syncthreads();  // S2

    // Y = M@X + Ce@h  (ycc[t 4][p 2], wave p-slab = 32 rows)
    f32x4 ycc[4][2];
#pragma unroll
    for (int i = 0; i < 4; ++i)
#pragma unroll
      for (int j = 0; j < 2; ++j) ycc[i][j] = (f32x4)0.f;
#pragma unroll
    for (int kk = 0; kk < 2; ++kk) {
      short8 av[4], bv[2];
#pragma unroll
      for (int i = 0; i < 4; ++i)
        av[i] = fragr(Mm, i * 16 + lrow, kk * 64 + lk * 16);
#pragma unroll
      for (int j = 0; j < 2; ++j)
        bv[j] = fragr(Xb, wave * 32 + j * 16 + lrow, kk * 64 + lk * 16);
#pragma unroll
      for (int i = 0; i < 4; ++i)
#pragma unroll
        for (int j = 0; j < 2; ++j)
          ycc[i][j] = __builtin_amdgcn_mfma_f32_16x16x32_bf16(av[i], bv[j], ycc[i][j], 0, 0, 0);
    }
#pragma unroll
    for (int kk = 0; kk < 2; ++kk) {
      short8 av[4], bv[2];
#pragma unroll
      for (int i = 0; i < 4; ++i)
        av[i] = fragr(Cn, i * 16 + lrow, kk * 64 + lk * 16);
#pragma unroll
      for (int j = 0; j < 2; ++j)
        bv[j] = fragr(Hb, wave * 32 + j * 16 + lrow, kk * 64 + lk * 16);
#pragma unroll
      for (int i = 0; i < 4; ++i)
#pragma unroll
        for (int j = 0; j < 2; ++j)
          ycc[i][j] = __builtin_amdgcn_mfma_f32_16x16x32_bf16(av[i], bv[j], ycc[i][j], 0, 0, 0);
    }
#pragma unroll
    for (int i = 0; i < 4; ++i)
#pragma unroll
      for (int j = 0; j < 2; ++j)
#pragma unroll
        for (int r = 0; r < 4; ++r) {
          int t = i * 16 + lk * 4 + r;
          int pl = wave * 32 + j * 16 + lrow;
          float xv = bf2f(*(const short*)(Xb + pl * 128 + ((t * 2) ^ ((pl & 7) << 4))));
          yfull[(size_t)(rowbase + s0 + t) * DINNER + h * HD + pbase + pl] = f2bf(ycc[i][j][r] + Dh * xv);
        }
    {  // scale Xb in place (wave-local rows, granule half by lane>>5)
      int row = wave * 32 + (lane & 31);
      int gb = (lane >> 5) * 4;
      float aend = aa[s0 + SC];
#pragma unroll
      for (int gi = 0; gi < 4; ++gi) {
        int g = gb + gi;
        int off = row * 128 + g * 16;
        int sb = s0 + (((g * 16) ^ ((row & 7) << 4)) >> 1);
        short8 v = *(short8*)(Xb + off);
        short8 o;
#pragma unroll
        for (int j = 0; j < 8; ++j)
          o[j] = f2bf(bf2f(v[j]) * __expf(aend - aa[sb + j + 1]) * dts[sb + j]);
        *(short8*)(Xb + off) = o;
      }
    }
    {  // h = P_sub*h + Xw^T @ B
      float Ps = __expf(aa[s0 + SC] - aa[s0]);
#pragma unroll
      for (int i = 0; i < 2; ++i)
#pragma unroll
        for (int j = 0; j < 4; ++j) hcc[i][j] *= Ps;
#pragma unroll
      for (int kk = 0; kk < 2; ++kk) {
        short8 av[2], bv[4];
#pragma unroll
        for (int i = 0; i < 2; ++i)
          av[i] = fragr(Xb, wave * 32 + i * 16 + lrow, kk * 64 + lk * 16);
#pragma unroll
        for (int j = 0; j < 4; ++j)
          bv[j] = fragr(Bt2, j * 16 + lrow, kk * 64 + lk * 16);
#pragma unroll
        for (int i = 0; i < 2; ++i)
#pragma unroll
          for (int j = 0; j < 4; ++j)
            hcc[i][j] = __builtin_amdgcn_mfma_f32_16x16x32_bf16(av[i], bv[j], hcc[i][j], 0, 0, 0);
      }
    }
    __syncthreads();  // S3
  }
}

// ---------------- gate (silu(z)) + RMSNorm -> bf16 ----------------
__global__ __launch_bounds__(256)
void gate_norm_kernel(const short* __restrict__ yfull, const short* __restrict__ zb,
                      const float* __restrict__ norm_w, short* __restrict__ yn) {
  int row = blockIdx.x, tid = threadIdx.x;
  size_t yb = (size_t)row * DINNER;
  float v[8];
  float ss = 0.f;
#pragma unroll
  for (int g = 0; g < 2; ++g) {
    int cidx = g * 1024 + tid * 4;
    short4v y4 = *(const short4v*)(yfull + yb + cidx);
    short4v z4 = *(const short4v*)(zb + yb + cidx);
#pragma unroll
    for (int j = 0; j < 4; ++j) {
      float z = bf2f(z4[j]);
      float val = bf2f(y4[j]) * z * sigmoidf_fast(z);
      v[g * 4 + j] = val;
      ss = fmaf(val, val, ss);
    }
  }
#pragma unroll
  for (int o = 32; o; o >>= 1) ss += __shfl_down(ss, o);
  __shared__ float red[4];
  if ((tid & 63) == 0) red[tid >> 6] = ss;
  __syncthreads();
  float tot = red[0] + red[1] + red[2] + red[3];
  float scale = rsqrtf(tot * (1.f / (float)DINNER) + 1e-5f);
#pragma unroll
  for (int g = 0; g < 2; ++g) {
    int cidx = g * 1024 + tid * 4;
    short4v o4;
#pragma unroll
    for (int j = 0; j < 4; ++j) o4[j] = f2bf(v[g * 4 + j] * scale * norm_w[cidx + j]);
    *(short4v*)(yn + yb + cidx) = o4;
  }
}

// ---------------- launcher ----------------
extern "C" void kernel_launch(void* const* d_in, const int* in_sizes, int n_in,
                              void* d_out, int out_size, void* d_ws, size_t ws_size,
                              hipStream_t stream) {
  (void)in_sizes; (void)n_in; (void)out_size; (void)ws_size;
  const float* x     = (const float*)d_in[0];
  const float* W_in  = (const float*)d_in[1];
  const float* convw = (const float*)d_in[2];
  const float* convb = (const float*)d_in[3];
  const float* dtb   = (const float*)d_in[4];
  const float* Alog  = (const float*)d_in[5];
  const float* Dp    = (const float*)d_in[6];
  const float* inis  = (const float*)d_in[7];
  const float* nw    = (const float*)d_in[8];
  const float* W_out = (const float*)d_in[9];
  const float* W_nl  = (const float*)d_in[10];
  const float* b_nl  = (const float*)d_in[11];
  float* out = (float*)d_out;
  char* ws = (char*)d_ws;

  short* woutT  = (short*)(ws + O_WOUT);
  short* wnlT   = (short*)(ws + O_WNL);
  float* dtg    = (float*)(ws + O_DT);
  float* ldA    = (float*)(ws + O_LDA);
  float* Pg     = (float*)(ws + O_PG);
  short* bTg    = (short*)(ws + O_BT);
  short* zb     = (short*)(ws + O_ZB);
  short* xbcpre = (short*)(ws + O_XBCPRE);
  short* Sg     = (short*)(ws + O_SG);
  short* Hg     = (short*)(ws + O_HG);
  short* tb     = (short*)(ws + O_TB);
  short* bc     = (short*)(ws + O_XBC);
  short* yn     = (short*)(ws + O_YN);
  short* xT     = (short*)(ws + O_XTR);
  short* xbf    = (short*)(ws + O_XBF);
  short* winT   = (short*)(ws + O_WIN);
  float* wtailT = (float*)(ws + O_WTAIL);
  short* yfull  = (short*)d_out;

  // wtail first (cast_dt depends on it), then merged transposes + cast/dt
  wtail_kernel<<<32, 256, 0, stream>>>(W_in, wtailT);
  prep_cast_kernel<<<1824 + ROWS, 256, 0, stream>>>(W_in, W_out, W_nl, winT, woutT, wnlT,
                                                    x, wtailT, dtb, Alog, xbf, dtg, ldA);

  // GEMM1: M=8192 (32 tiles of 256), N=4224 (33 tiles of 128), K=1024 -> 1056 blocks
  gemm1_256<<<32 * 33, 512, 0, stream>>>(xbf, winT, HM, 33, zb, xbcpre);
  conv_silu_kernel<<<17 * 32 * 4, 256, 0, stream>>>(xbcpre, convw, convb, bc, xT, bTg);

  scan_passA_mfma<<<32 * NC * 2, 256, 0, stream>>>(xT, bTg, dtg, ldA, Sg, Pg);
  scan_passB<<<32 * 16, 256, 0, stream>>>(Sg, Pg, inis, Hg);
  scan_passC_mfma<<<32 * NC * 2, 256, 0, stream>>>(xT, bTg, bc, dtg, ldA, Hg, Dp, yfull);

  gate_norm_kernel<<<ROWS, 256, 0, stream>>>(yfull, zb, nw, yn);
  // GEMM2: M=8192, N=1024 (8x128), K=2048 -> 256 blocks
  gemm8p<1><<<32 * 8, 512, 0, stream>>>(yn, woutT, DINNER, 8, HM, nullptr, tb, nullptr, nullptr);
  // GEMM3: M=8192, N=1024, K=1024 -> 256 blocks
  gemm8p<2><<<32 * 8, 512, 0, stream>>>(tb, wnlT, HM, 8, HM, out, nullptr, b_nl, x);
}